// Round 3
// baseline (529.402 us; speedup 1.0000x reference)
//
#include <hip/hip_runtime.h>
#include <math.h>

#define N_NODES 50000
#define N_EDGES 800000
#define VOCAB 100
#define DIM 128
#define N_GRAPHS 512
#define LN_EPS 1e-5f

__device__ __forceinline__ unsigned short f2bf(float f) {
    unsigned u = __float_as_uint(f);
    return (unsigned short)((u + 0x7FFF + ((u >> 16) & 1)) >> 16);  // RNE
}

// ---------------- degree ----------------
__global__ void k_deg(const int* __restrict__ dst, int* __restrict__ deg) {
    int e = blockIdx.x * blockDim.x + threadIdx.x;
    if (e < N_EDGES) atomicAdd(&deg[dst[e]], 1);
}

// ---------------- graph starts via binary search (batch is sorted) ----------------
__global__ void k_starts(const int* __restrict__ batch, int* __restrict__ starts) {
    int g = blockIdx.x * blockDim.x + threadIdx.x;
    if (g > N_GRAPHS) return;
    int lo = 0, hi = N_NODES;
    while (lo < hi) { int mid = (lo + hi) >> 1; if (batch[mid] < g) lo = mid + 1; else hi = mid; }
    starts[g] = lo;
}

// ---------------- single-block scan over deg -> rowstart, + dinv ----------------
__global__ __launch_bounds__(1024) void k_scan(const int* __restrict__ deg,
                                               int* __restrict__ rowstart,
                                               float* __restrict__ dinv) {
    __shared__ int sums[1024];
    int tid = threadIdx.x;
    const int chunk = (N_NODES + 1023) / 1024;
    int begin = tid * chunk;
    int end = begin + chunk;
    if (end > N_NODES) end = N_NODES;
    int s = 0;
    for (int i = begin; i < end; i++) s += deg[i];
    sums[tid] = s;
    __syncthreads();
    for (int off = 1; off < 1024; off <<= 1) {
        int v = (tid >= off) ? sums[tid - off] : 0;
        __syncthreads();
        sums[tid] += v;
        __syncthreads();
    }
    int run = (tid > 0) ? sums[tid - 1] : 0;
    for (int i = begin; i < end; i++) {
        int d = deg[i];
        rowstart[i] = run; run += d;
        dinv[i] = rsqrtf((float)d + 1.0f);
    }
    if (begin < N_NODES && end == N_NODES) rowstart[N_NODES] = run;
}

// ---------------- S[dst, x[src]] += dinv[src]  (layer-1 one-hot trick) ----------------
__global__ void k_smat(const int* __restrict__ src, const int* __restrict__ dst,
                       const int* __restrict__ x, const float* __restrict__ dinv,
                       float* __restrict__ S) {
    int e = blockIdx.x * blockDim.x + threadIdx.x;
    if (e >= N_EDGES) return;
    int s = src[e];
    atomicAdd(&S[dst[e] * VOCAB + x[s]], dinv[s]);
}

// self-loop coefficient: S[i, x_i] += dinv_i  (whole row later scaled by dinv_i)
__global__ void k_self(const int* __restrict__ x, const float* __restrict__ dinv,
                       float* __restrict__ S) {
    int i = blockIdx.x * blockDim.x + threadIdx.x;
    if (i < N_NODES) S[i * VOCAB + x[i]] += dinv[i];
}

// ---------------- CSR scatter (4 B per edge only) ----------------
__global__ void k_scatter(const int* __restrict__ src, const int* __restrict__ dst,
                          const int* __restrict__ rowstart, int* __restrict__ cursor,
                          int* __restrict__ csr_src) {
    int e = blockIdx.x * blockDim.x + threadIdx.x;
    if (e >= N_EDGES) return;
    int d = dst[e];
    int pos = rowstart[d] + atomicAdd(&cursor[d], 1);
    csr_src[pos] = src[e];
}

// ---------------- EW1 = emb @ W1 (tiny: 100x128) ----------------
__global__ void k_ew1(const float* __restrict__ emb, const float* __restrict__ W1,
                      float* __restrict__ EW1) {
    int idx = blockIdx.x * blockDim.x + threadIdx.x;
    if (idx >= VOCAB * DIM) return;
    int r = idx >> 7, c = idx & 127;
    float acc = 0.f;
    for (int k = 0; k < DIM; k++) acc += emb[r * DIM + k] * W1[k * DIM + c];
    EW1[idx] = acc;
}

// ---------------- h1 = ReLU(LN(dinv * (S @ EW1) + b1))  dense K=100 matmul ----------------
// col mapping: thread (ty,tx) handles row ty, cols {j*32 + tx*4 .. +3} -> conflict-free
#define SW 104  // srow LDS stride (104%32=8 -> 2-way on b32 reads, free)
__global__ __launch_bounds__(256) void k_h1(
    const float* __restrict__ S, const float* __restrict__ EW1,
    const float* __restrict__ dinv, const float* __restrict__ b1,
    const float* __restrict__ g1, const float* __restrict__ be1,
    float* __restrict__ h1) {
    __shared__ float ew[VOCAB * DIM];   // 51200 B
    __shared__ float srow[32 * SW];     // 13312 B
    int t = threadIdx.x;
    for (int idx = t * 4; idx < VOCAB * DIM; idx += 1024)
        *(float4*)&ew[idx] = *(const float4*)&EW1[idx];
    int row0 = blockIdx.x * 32;
    for (int idx = t; idx < 32 * VOCAB; idx += 256) {
        int r = idx / VOCAB, k = idx - r * VOCAB;
        int g = row0 * VOCAB + idx;
        srow[r * SW + k] = (g < N_NODES * VOCAB) ? S[g] : 0.f;
    }
    __syncthreads();
    int ty = t >> 3, tx = t & 7;
    float4 acc[4];
    #pragma unroll
    for (int j = 0; j < 4; j++) acc[j] = make_float4(0.f, 0.f, 0.f, 0.f);
    for (int k = 0; k < VOCAB; k++) {
        float a = srow[ty * SW + k];
        #pragma unroll
        for (int j = 0; j < 4; j++) {
            float4 wv = *(float4*)&ew[k * DIM + j * 32 + tx * 4];
            acc[j].x += a * wv.x; acc[j].y += a * wv.y;
            acc[j].z += a * wv.z; acc[j].w += a * wv.w;
        }
    }
    int row = row0 + ty;
    if (row >= N_NODES) return;
    float di = dinv[row];
    float vals[16];
    float s = 0.f;
    #pragma unroll
    for (int j = 0; j < 4; j++) {
        int col = j * 32 + tx * 4;
        float4 bv = *(const float4*)&b1[col];
        vals[j*4+0] = di * acc[j].x + bv.x; vals[j*4+1] = di * acc[j].y + bv.y;
        vals[j*4+2] = di * acc[j].z + bv.z; vals[j*4+3] = di * acc[j].w + bv.w;
        s += vals[j*4+0] + vals[j*4+1] + vals[j*4+2] + vals[j*4+3];
    }
    #pragma unroll
    for (int m = 1; m < 8; m <<= 1) s += __shfl_xor(s, m, 8);
    float mu = s * (1.f / 128.f);
    float q = 0.f;
    #pragma unroll
    for (int u = 0; u < 16; u++) { float d = vals[u] - mu; q += d * d; }
    #pragma unroll
    for (int m = 1; m < 8; m <<= 1) q += __shfl_xor(q, m, 8);
    float rs = rsqrtf(q * (1.f / 128.f) + LN_EPS);
    #pragma unroll
    for (int j = 0; j < 4; j++) {
        int col = j * 32 + tx * 4;
        float4 gv = *(const float4*)&g1[col];
        float4 ev = *(const float4*)&be1[col];
        float4 o;
        o.x = fmaxf((vals[j*4+0] - mu) * rs * gv.x + ev.x, 0.f);
        o.y = fmaxf((vals[j*4+1] - mu) * rs * gv.y + ev.y, 0.f);
        o.z = fmaxf((vals[j*4+2] - mu) * rs * gv.z + ev.z, 0.f);
        o.w = fmaxf((vals[j*4+3] - mu) * rs * gv.w + ev.w, 0.f);
        *(float4*)&h1[row * DIM + col] = o;
    }
}

// ---------------- v2 = bf16( dinv * (h1 @ W2) ), W2 in LDS ----------------
#define HTW 132  // ht stride: (132%32=4) -> conflict-free b32 reads across ty; /4 for float4
__global__ __launch_bounds__(256) void k_mm2(
    const float* __restrict__ h1, const float* __restrict__ W2,
    const float* __restrict__ dinv, unsigned short* __restrict__ v2b) {
    __shared__ float w[DIM * DIM];    // 65536 B
    __shared__ float ht[32 * HTW];    // 16896 B
    int t = threadIdx.x;
    for (int idx = t * 4; idx < DIM * DIM; idx += 1024)
        *(float4*)&w[idx] = *(const float4*)&W2[idx];
    int row0 = blockIdx.x * 32;
    for (int idx = t * 4; idx < 32 * DIM; idx += 1024) {
        int r = idx >> 7, c = idx & 127;
        int row = row0 + r;
        float4 val = make_float4(0.f, 0.f, 0.f, 0.f);
        if (row < N_NODES) val = *(const float4*)&h1[row * DIM + c];
        *(float4*)&ht[r * HTW + c] = val;
    }
    __syncthreads();
    int ty = t >> 3, tx = t & 7;
    float4 acc[4];
    #pragma unroll
    for (int j = 0; j < 4; j++) acc[j] = make_float4(0.f, 0.f, 0.f, 0.f);
    for (int k = 0; k < DIM; k++) {
        float a = ht[ty * HTW + k];
        #pragma unroll
        for (int j = 0; j < 4; j++) {
            float4 wv = *(float4*)&w[k * DIM + j * 32 + tx * 4];
            acc[j].x += a * wv.x; acc[j].y += a * wv.y;
            acc[j].z += a * wv.z; acc[j].w += a * wv.w;
        }
    }
    int row = row0 + ty;
    if (row < N_NODES) {
        float di = dinv[row];
        #pragma unroll
        for (int j = 0; j < 4; j++) {
            int col = j * 32 + tx * 4;
            unsigned lo = (unsigned)f2bf(di * acc[j].x) | ((unsigned)f2bf(di * acc[j].y) << 16);
            unsigned hi = (unsigned)f2bf(di * acc[j].z) | ((unsigned)f2bf(di * acc[j].w) << 16);
            uint2 pk = make_uint2(lo, hi);
            *(uint2*)&v2b[row * DIM + col] = pk;
        }
    }
}

// ---------------- layer-2 agg (bf16 gathers) + LN + ReLU + fused pool sums ----------------
__global__ __launch_bounds__(256) void k_agg2(
    const unsigned* __restrict__ v2u, const float* __restrict__ dinv,
    const int* __restrict__ rowstart, const int* __restrict__ csr_src,
    const int* __restrict__ batch,
    const float* __restrict__ b2, const float* __restrict__ g2,
    const float* __restrict__ be2, float* __restrict__ pooled) {
    int lane = threadIdx.x & 63;
    int wave = (blockIdx.x * blockDim.x + threadIdx.x) >> 6;
    int nw = (gridDim.x * blockDim.x) >> 6;
    float2 bb = make_float2(b2[2 * lane], b2[2 * lane + 1]);
    float2 gg = make_float2(g2[2 * lane], g2[2 * lane + 1]);
    float2 eb = make_float2(be2[2 * lane], be2[2 * lane + 1]);
    for (int i = wave; i < N_NODES; i += nw) {
        float di = dinv[i];
        unsigned u0 = v2u[i * 64 + lane];  // self term (dinv_i*hW_i folded in v2)
        float ax = __uint_as_float(u0 << 16);
        float ay = __uint_as_float(u0 & 0xFFFF0000u);
        int p = rowstart[i], pe = rowstart[i + 1];
        while (p < pe) {
            int n = pe - p; if (n > 64) n = 64;
            int mys = 0;
            if (lane < n) mys = csr_src[p + lane];
            int j = 0;
            for (; j + 8 <= n; j += 8) {
                #pragma unroll
                for (int u = 0; u < 8; u++) {
                    int s = __shfl(mys, j + u, 64);
                    unsigned uv = v2u[s * 64 + lane];
                    ax += __uint_as_float(uv << 16);
                    ay += __uint_as_float(uv & 0xFFFF0000u);
                }
            }
            for (; j < n; j++) {
                int s = __shfl(mys, j, 64);
                unsigned uv = v2u[s * 64 + lane];
                ax += __uint_as_float(uv << 16);
                ay += __uint_as_float(uv & 0xFFFF0000u);
            }
            p += n;
        }
        float a0 = di * ax + bb.x, a1 = di * ay + bb.y;
        float s = a0 + a1;
        #pragma unroll
        for (int m = 1; m < 64; m <<= 1) s += __shfl_xor(s, m, 64);
        float mu = s * (1.f / 128.f);
        float d0 = a0 - mu, d1 = a1 - mu;
        float q = d0 * d0 + d1 * d1;
        #pragma unroll
        for (int m = 1; m < 64; m <<= 1) q += __shfl_xor(q, m, 64);
        float r = rsqrtf(q * (1.f / 128.f) + LN_EPS);
        float o0 = fmaxf(d0 * r * gg.x + eb.x, 0.f);
        float o1 = fmaxf(d1 * r * gg.y + eb.y, 0.f);
        int g = batch[i];
        atomicAdd(&pooled[g * DIM + 2 * lane], o0);
        atomicAdd(&pooled[g * DIM + 2 * lane + 1], o1);
    }
}

// ---------------- out[g] = pooled[g].fcW / max(cnt,1) + fcb ----------------
__global__ void k_out(const float* __restrict__ pooled, const int* __restrict__ starts,
                      const float* __restrict__ fcW, const float* __restrict__ fcb,
                      float* __restrict__ out) {
    int lane = threadIdx.x & 63;
    int g = (blockIdx.x * blockDim.x + threadIdx.x) >> 6;
    if (g >= N_GRAPHS) return;
    float2 p = ((const float2*)pooled)[g * 64 + lane];
    float2 w = ((const float2*)fcW)[lane];
    float s = p.x * w.x + p.y * w.y;
    #pragma unroll
    for (int m = 1; m < 64; m <<= 1) s += __shfl_xor(s, m, 64);
    if (lane == 0) {
        float c = (float)(starts[g + 1] - starts[g]);
        if (c < 1.f) c = 1.f;
        out[g] = s / c + fcb[0];
    }
}

extern "C" void kernel_launch(void* const* d_in, const int* in_sizes, int n_in,
                              void* d_out, int out_size, void* d_ws, size_t ws_size,
                              hipStream_t stream) {
    (void)in_sizes; (void)n_in; (void)out_size; (void)ws_size;
    const int* x    = (const int*)d_in[0];
    const int* src  = (const int*)d_in[1];
    const int* dst  = src + N_EDGES;
    const int* batch = (const int*)d_in[2];
    const float* emb = (const float*)d_in[3];
    const float* W1  = (const float*)d_in[4];
    const float* b1  = (const float*)d_in[5];
    const float* g1  = (const float*)d_in[6];
    const float* be1 = (const float*)d_in[7];
    const float* W2  = (const float*)d_in[8];
    const float* b2  = (const float*)d_in[9];
    const float* g2  = (const float*)d_in[10];
    const float* be2 = (const float*)d_in[11];
    const float* fcW = (const float*)d_in[12];
    const float* fcb = (const float*)d_in[13];
    float* out = (float*)d_out;

    char* wsp = (char*)d_ws;
    size_t off = 0;
    auto alloc = [&](size_t bytes) -> void* {
        void* p = wsp + off;
        off += (bytes + 15) & ~(size_t)15;
        return p;
    };
    // ---- zeroed region ----
    int*   deg      = (int*)alloc(N_NODES * 4);
    int*   cursor   = (int*)alloc(N_NODES * 4);
    float* pooled   = (float*)alloc(N_GRAPHS * DIM * 4);
    float* S        = (float*)alloc((size_t)N_NODES * VOCAB * 4);  // 20 MB
    size_t zero_bytes = off;
    // ---- scratch ----
    int*   rowstart = (int*)alloc((N_NODES + 1) * 4);
    float* dinv     = (float*)alloc(N_NODES * 4);
    int*   csr_src  = (int*)alloc(N_EDGES * 4);
    float* EW1      = (float*)alloc(VOCAB * DIM * 4);
    int*   starts   = (int*)alloc((N_GRAPHS + 1) * 4);
    float* h1       = (float*)alloc((size_t)N_NODES * DIM * 4);
    unsigned short* v2b = (unsigned short*)alloc((size_t)N_NODES * DIM * 2);

    hipMemsetAsync(d_ws, 0, zero_bytes, stream);

    k_deg<<<(N_EDGES + 255) / 256, 256, 0, stream>>>(dst, deg);
    k_starts<<<3, 256, 0, stream>>>(batch, starts);
    k_scan<<<1, 1024, 0, stream>>>(deg, rowstart, dinv);
    k_smat<<<(N_EDGES + 255) / 256, 256, 0, stream>>>(src, dst, x, dinv, S);
    k_self<<<(N_NODES + 255) / 256, 256, 0, stream>>>(x, dinv, S);
    k_scatter<<<(N_EDGES + 255) / 256, 256, 0, stream>>>(src, dst, rowstart, cursor, csr_src);
    k_ew1<<<(VOCAB * DIM + 255) / 256, 256, 0, stream>>>(emb, W1, EW1);
    k_h1<<<(N_NODES + 31) / 32, 256, 0, stream>>>(S, EW1, dinv, b1, g1, be1, h1);
    k_mm2<<<(N_NODES + 31) / 32, 256, 0, stream>>>(h1, W2, dinv, v2b);
    k_agg2<<<2048, 256, 0, stream>>>((const unsigned*)v2b, dinv, rowstart, csr_src, batch,
                                     b2, g2, be2, pooled);
    k_out<<<(N_GRAPHS * 64 + 255) / 256, 256, 0, stream>>>(pooled, starts, fcW, fcb, out);
}

// Round 4
// 371.324 us; speedup vs baseline: 1.4257x; 1.4257x over previous
//
#include <hip/hip_runtime.h>
#include <math.h>

#define N_NODES 50000
#define N_EDGES 800000
#define VOCAB 100
#define DIM 128
#define N_GRAPHS 512
#define LN_EPS 1e-5f
#define NB 196  // ceil(N_NODES/256)

__device__ __forceinline__ unsigned short f2bf(float f) {
    unsigned u = __float_as_uint(f);
    return (unsigned short)((u + 0x7FFF + ((u >> 16) & 1)) >> 16);  // RNE
}

// ---------------- degree ----------------
__global__ void k_deg(const int* __restrict__ dst, int* __restrict__ deg) {
    int e = blockIdx.x * blockDim.x + threadIdx.x;
    if (e < N_EDGES) atomicAdd(&deg[dst[e]], 1);
}

// ---------------- graph starts via binary search (batch is sorted) ----------------
__global__ void k_starts(const int* __restrict__ batch, int* __restrict__ starts) {
    int g = blockIdx.x * blockDim.x + threadIdx.x;
    if (g > N_GRAPHS) return;
    int lo = 0, hi = N_NODES;
    while (lo < hi) { int mid = (lo + hi) >> 1; if (batch[mid] < g) lo = mid + 1; else hi = mid; }
    starts[g] = lo;
}

// ---------------- 3-phase multi-block scan ----------------
__global__ __launch_bounds__(256) void kb_sum(const int* __restrict__ deg,
                                              int* __restrict__ bsum) {
    int i = blockIdx.x * 256 + threadIdx.x;
    int v = (i < N_NODES) ? deg[i] : 0;
    #pragma unroll
    for (int m = 1; m < 64; m <<= 1) v += __shfl_xor(v, m, 64);
    __shared__ int ws[4];
    int lane = threadIdx.x & 63, w = threadIdx.x >> 6;
    if (lane == 0) ws[w] = v;
    __syncthreads();
    if (threadIdx.x == 0) bsum[blockIdx.x] = ws[0] + ws[1] + ws[2] + ws[3];
}

__global__ __launch_bounds__(256) void kb_scan(const int* __restrict__ bsum,
                                               int* __restrict__ bofs,
                                               int* __restrict__ rowstart) {
    int t = threadIdx.x, lane = t & 63, w = t >> 6;
    int v = (t < NB) ? bsum[t] : 0;
    int incl = v;
    #pragma unroll
    for (int off = 1; off < 64; off <<= 1) {
        int u = __shfl_up(incl, off, 64);
        if (lane >= off) incl += u;
    }
    __shared__ int ws[4];
    if (lane == 63) ws[w] = incl;
    __syncthreads();
    int add = 0;
    for (int k = 0; k < w; k++) add += ws[k];
    incl += add;
    if (t < NB) bofs[t] = incl - v;
    if (t == 255) rowstart[N_NODES] = incl;
}

__global__ __launch_bounds__(256) void kb_emit(const int* __restrict__ deg,
                                               const int* __restrict__ bofs,
                                               const int* __restrict__ x,
                                               int* __restrict__ rowstart,
                                               float* __restrict__ dinv,
                                               int2* __restrict__ xd) {
    int b = blockIdx.x, t = threadIdx.x, i = b * 256 + t;
    int lane = t & 63, w = t >> 6;
    int v = (i < N_NODES) ? deg[i] : 0;
    int incl = v;
    #pragma unroll
    for (int off = 1; off < 64; off <<= 1) {
        int u = __shfl_up(incl, off, 64);
        if (lane >= off) incl += u;
    }
    __shared__ int ws[4];
    if (lane == 63) ws[w] = incl;
    __syncthreads();
    int add = bofs[b];
    for (int k = 0; k < w; k++) add += ws[k];
    if (i < N_NODES) {
        rowstart[i] = add + incl - v;
        float dv = rsqrtf((float)v + 1.0f);
        dinv[i] = dv;
        xd[i] = make_int2(x[i], __float_as_int(dv));
    }
}

// ---------------- CSR scatter (4 B per edge) ----------------
__global__ void k_scatter(const int* __restrict__ src, const int* __restrict__ dst,
                          const int* __restrict__ rowstart, int* __restrict__ cursor,
                          int* __restrict__ csr_src) {
    int e = blockIdx.x * blockDim.x + threadIdx.x;
    if (e >= N_EDGES) return;
    int d = dst[e];
    int pos = rowstart[d] + atomicAdd(&cursor[d], 1);
    csr_src[pos] = src[e];
}

// ---------------- EW1 = emb @ W1 (tiny: 100x128) ----------------
__global__ void k_ew1(const float* __restrict__ emb, const float* __restrict__ W1,
                      float* __restrict__ EW1) {
    int idx = blockIdx.x * blockDim.x + threadIdx.x;
    if (idx >= VOCAB * DIM) return;
    int r = idx >> 7, c = idx & 127;
    float acc = 0.f;
    for (int k = 0; k < DIM; k++) acc += emb[r * DIM + k] * W1[k * DIM + c];
    EW1[idx] = acc;
}

// ---------------- layer-1 agg + LN + ReLU (EW1 in LDS, chunked broadcast) ----------------
__global__ __launch_bounds__(256) void k_agg1(
    const float* __restrict__ EW1, const int2* __restrict__ xd,
    const int* __restrict__ rowstart, const int* __restrict__ csr_src,
    const float* __restrict__ b1, const float* __restrict__ g1,
    const float* __restrict__ be1, float2* __restrict__ h1) {
    __shared__ float2 ew[VOCAB * 64];  // 51200 B
    for (int idx = threadIdx.x; idx < VOCAB * 64; idx += blockDim.x)
        ew[idx] = ((const float2*)EW1)[idx];
    __syncthreads();
    int lane = threadIdx.x & 63;
    int wave = (blockIdx.x * blockDim.x + threadIdx.x) >> 6;
    int nw = (gridDim.x * blockDim.x) >> 6;
    float2 bb = make_float2(b1[2 * lane], b1[2 * lane + 1]);
    float2 gg = make_float2(g1[2 * lane], g1[2 * lane + 1]);
    float2 eb = make_float2(be1[2 * lane], be1[2 * lane + 1]);
    for (int i = wave; i < N_NODES; i += nw) {
        int2 self = xd[i];
        float di = __int_as_float(self.y);
        float2 e0 = ew[self.x * 64 + lane];
        float ax = di * e0.x, ay = di * e0.y;  // self-loop: dinv_i * EW1[x_i]
        int p = rowstart[i], pe = rowstart[i + 1];
        while (p < pe) {
            int n = pe - p; if (n > 64) n = 64;
            int2 my = make_int2(0, 0);
            if (lane < n) { int s = csr_src[p + lane]; my = xd[s]; }
            int j = 0;
            for (; j + 8 <= n; j += 8) {
                #pragma unroll
                for (int u = 0; u < 8; u++) {
                    int xv = __shfl(my.x, j + u, 64);
                    float ds = __int_as_float(__shfl(my.y, j + u, 64));
                    float2 es = ew[xv * 64 + lane];
                    ax += ds * es.x; ay += ds * es.y;
                }
            }
            for (; j < n; j++) {
                int xv = __shfl(my.x, j, 64);
                float ds = __int_as_float(__shfl(my.y, j, 64));
                float2 es = ew[xv * 64 + lane];
                ax += ds * es.x; ay += ds * es.y;
            }
            p += n;
        }
        float a0 = di * ax + bb.x, a1 = di * ay + bb.y;
        float s = a0 + a1;
        #pragma unroll
        for (int m = 1; m < 64; m <<= 1) s += __shfl_xor(s, m, 64);
        float mu = s * (1.f / 128.f);
        float d0 = a0 - mu, d1 = a1 - mu;
        float q = d0 * d0 + d1 * d1;
        #pragma unroll
        for (int m = 1; m < 64; m <<= 1) q += __shfl_xor(q, m, 64);
        float r = rsqrtf(q * (1.f / 128.f) + LN_EPS);
        float o0 = fmaxf(d0 * r * gg.x + eb.x, 0.f);
        float o1 = fmaxf(d1 * r * gg.y + eb.y, 0.f);
        h1[i * 64 + lane] = make_float2(o0, o1);
    }
}

// ---------------- v2 = bf16( dinv * (h1 @ W2) ), W2 in LDS ----------------
#define HTW 132  // ht stride: 132%32=4 -> conflict-free b32 reads across ty
__global__ __launch_bounds__(256) void k_mm2(
    const float* __restrict__ h1, const float* __restrict__ W2,
    const float* __restrict__ dinv, unsigned short* __restrict__ v2b) {
    __shared__ float w[DIM * DIM];    // 65536 B
    __shared__ float ht[32 * HTW];    // 16896 B
    int t = threadIdx.x;
    for (int idx = t * 4; idx < DIM * DIM; idx += 1024)
        *(float4*)&w[idx] = *(const float4*)&W2[idx];
    int row0 = blockIdx.x * 32;
    for (int idx = t * 4; idx < 32 * DIM; idx += 1024) {
        int r = idx >> 7, c = idx & 127;
        int row = row0 + r;
        float4 val = make_float4(0.f, 0.f, 0.f, 0.f);
        if (row < N_NODES) val = *(const float4*)&h1[row * DIM + c];
        *(float4*)&ht[r * HTW + c] = val;
    }
    __syncthreads();
    int ty = t >> 3, tx = t & 7;
    float4 acc[4];
    #pragma unroll
    for (int j = 0; j < 4; j++) acc[j] = make_float4(0.f, 0.f, 0.f, 0.f);
    for (int k = 0; k < DIM; k++) {
        float a = ht[ty * HTW + k];
        #pragma unroll
        for (int j = 0; j < 4; j++) {
            float4 wv = *(float4*)&w[k * DIM + j * 32 + tx * 4];
            acc[j].x += a * wv.x; acc[j].y += a * wv.y;
            acc[j].z += a * wv.z; acc[j].w += a * wv.w;
        }
    }
    int row = row0 + ty;
    if (row < N_NODES) {
        float di = dinv[row];
        #pragma unroll
        for (int j = 0; j < 4; j++) {
            int col = j * 32 + tx * 4;
            unsigned lo = (unsigned)f2bf(di * acc[j].x) | ((unsigned)f2bf(di * acc[j].y) << 16);
            unsigned hi = (unsigned)f2bf(di * acc[j].z) | ((unsigned)f2bf(di * acc[j].w) << 16);
            uint2 pk = make_uint2(lo, hi);
        *(uint2*)&v2b[row * DIM + col] = pk;
        }
    }
}

// ---------------- layer-2 agg (bf16 gathers) + LN + ReLU + fused pool sums ----------------
__global__ __launch_bounds__(256) void k_agg2(
    const unsigned* __restrict__ v2u, const float* __restrict__ dinv,
    const int* __restrict__ rowstart, const int* __restrict__ csr_src,
    const int* __restrict__ batch,
    const float* __restrict__ b2, const float* __restrict__ g2,
    const float* __restrict__ be2, float* __restrict__ pooled) {
    int lane = threadIdx.x & 63;
    int wave = (blockIdx.x * blockDim.x + threadIdx.x) >> 6;
    int nw = (gridDim.x * blockDim.x) >> 6;
    float2 bb = make_float2(b2[2 * lane], b2[2 * lane + 1]);
    float2 gg = make_float2(g2[2 * lane], g2[2 * lane + 1]);
    float2 eb = make_float2(be2[2 * lane], be2[2 * lane + 1]);
    for (int i = wave; i < N_NODES; i += nw) {
        float di = dinv[i];
        unsigned u0 = v2u[i * 64 + lane];  // self term (dinv_i*hW_i folded in v2)
        float ax = __uint_as_float(u0 << 16);
        float ay = __uint_as_float(u0 & 0xFFFF0000u);
        int p = rowstart[i], pe = rowstart[i + 1];
        while (p < pe) {
            int n = pe - p; if (n > 64) n = 64;
            int mys = 0;
            if (lane < n) mys = csr_src[p + lane];
            int j = 0;
            for (; j + 8 <= n; j += 8) {
                #pragma unroll
                for (int u = 0; u < 8; u++) {
                    int s = __shfl(mys, j + u, 64);
                    unsigned uv = v2u[s * 64 + lane];
                    ax += __uint_as_float(uv << 16);
                    ay += __uint_as_float(uv & 0xFFFF0000u);
                }
            }
            for (; j < n; j++) {
                int s = __shfl(mys, j, 64);
                unsigned uv = v2u[s * 64 + lane];
                ax += __uint_as_float(uv << 16);
                ay += __uint_as_float(uv & 0xFFFF0000u);
            }
            p += n;
        }
        float a0 = di * ax + bb.x, a1 = di * ay + bb.y;
        float s = a0 + a1;
        #pragma unroll
        for (int m = 1; m < 64; m <<= 1) s += __shfl_xor(s, m, 64);
        float mu = s * (1.f / 128.f);
        float d0 = a0 - mu, d1 = a1 - mu;
        float q = d0 * d0 + d1 * d1;
        #pragma unroll
        for (int m = 1; m < 64; m <<= 1) q += __shfl_xor(q, m, 64);
        float r = rsqrtf(q * (1.f / 128.f) + LN_EPS);
        float o0 = fmaxf(d0 * r * gg.x + eb.x, 0.f);
        float o1 = fmaxf(d1 * r * gg.y + eb.y, 0.f);
        int g = batch[i];
        atomicAdd(&pooled[g * DIM + 2 * lane], o0);
        atomicAdd(&pooled[g * DIM + 2 * lane + 1], o1);
    }
}

// ---------------- out[g] = pooled[g].fcW / max(cnt,1) + fcb ----------------
__global__ void k_out(const float* __restrict__ pooled, const int* __restrict__ starts,
                      const float* __restrict__ fcW, const float* __restrict__ fcb,
                      float* __restrict__ out) {
    int lane = threadIdx.x & 63;
    int g = (blockIdx.x * blockDim.x + threadIdx.x) >> 6;
    if (g >= N_GRAPHS) return;
    float2 p = ((const float2*)pooled)[g * 64 + lane];
    float2 w = ((const float2*)fcW)[lane];
    float s = p.x * w.x + p.y * w.y;
    #pragma unroll
    for (int m = 1; m < 64; m <<= 1) s += __shfl_xor(s, m, 64);
    if (lane == 0) {
        float c = (float)(starts[g + 1] - starts[g]);
        if (c < 1.f) c = 1.f;
        out[g] = s / c + fcb[0];
    }
}

extern "C" void kernel_launch(void* const* d_in, const int* in_sizes, int n_in,
                              void* d_out, int out_size, void* d_ws, size_t ws_size,
                              hipStream_t stream) {
    (void)in_sizes; (void)n_in; (void)out_size; (void)ws_size;
    const int* x    = (const int*)d_in[0];
    const int* src  = (const int*)d_in[1];
    const int* dst  = src + N_EDGES;
    const int* batch = (const int*)d_in[2];
    const float* emb = (const float*)d_in[3];
    const float* W1  = (const float*)d_in[4];
    const float* b1  = (const float*)d_in[5];
    const float* g1  = (const float*)d_in[6];
    const float* be1 = (const float*)d_in[7];
    const float* W2  = (const float*)d_in[8];
    const float* b2  = (const float*)d_in[9];
    const float* g2  = (const float*)d_in[10];
    const float* be2 = (const float*)d_in[11];
    const float* fcW = (const float*)d_in[12];
    const float* fcb = (const float*)d_in[13];
    float* out = (float*)d_out;

    char* wsp = (char*)d_ws;
    size_t off = 0;
    auto alloc = [&](size_t bytes) -> void* {
        void* p = wsp + off;
        off += (bytes + 15) & ~(size_t)15;
        return p;
    };
    // ---- zeroed region ----
    int*   deg      = (int*)alloc(N_NODES * 4);
    int*   cursor   = (int*)alloc(N_NODES * 4);
    float* pooled   = (float*)alloc(N_GRAPHS * DIM * 4);
    size_t zero_bytes = off;
    // ---- scratch ----
    int*   rowstart = (int*)alloc((N_NODES + 1) * 4);
    float* dinv     = (float*)alloc(N_NODES * 4);
    int2*  xd       = (int2*)alloc((size_t)N_NODES * 8);
    int*   csr_src  = (int*)alloc(N_EDGES * 4);
    float* EW1      = (float*)alloc(VOCAB * DIM * 4);
    int*   starts   = (int*)alloc((N_GRAPHS + 1) * 4);
    int*   bsum     = (int*)alloc(NB * 4);
    int*   bofs     = (int*)alloc(NB * 4);
    float* h1       = (float*)alloc((size_t)N_NODES * DIM * 4);
    unsigned short* v2b = (unsigned short*)alloc((size_t)N_NODES * DIM * 2);

    hipMemsetAsync(d_ws, 0, zero_bytes, stream);

    k_deg<<<(N_EDGES + 255) / 256, 256, 0, stream>>>(dst, deg);
    k_starts<<<3, 256, 0, stream>>>(batch, starts);
    kb_sum<<<NB, 256, 0, stream>>>(deg, bsum);
    kb_scan<<<1, 256, 0, stream>>>(bsum, bofs, rowstart);
    kb_emit<<<NB, 256, 0, stream>>>(deg, bofs, x, rowstart, dinv, xd);
    k_scatter<<<(N_EDGES + 255) / 256, 256, 0, stream>>>(src, dst, rowstart, cursor, csr_src);
    k_ew1<<<(VOCAB * DIM + 255) / 256, 256, 0, stream>>>(emb, W1, EW1);
    // 768 blocks = 3 blocks/CU (LDS-capped), no scheduling tail
    k_agg1<<<768, 256, 0, stream>>>(EW1, xd, rowstart, csr_src, b1, g1, be1, (float2*)h1);
    k_mm2<<<(N_NODES + 31) / 32, 256, 0, stream>>>(h1, W2, dinv, v2b);
    k_agg2<<<2048, 256, 0, stream>>>((const unsigned*)v2b, dinv, rowstart, csr_src, batch,
                                     b2, g2, be2, pooled);
    k_out<<<(N_GRAPHS * 64 + 255) / 256, 256, 0, stream>>>(pooled, starts, fcW, fcb, out);
}

// Round 5
// 326.189 us; speedup vs baseline: 1.6230x; 1.1384x over previous
//
#include <hip/hip_runtime.h>
#include <math.h>

#define N_NODES 50000
#define N_EDGES 800000
#define VOCAB 100
#define DIM 128
#define N_GRAPHS 512
#define LN_EPS 1e-5f
#define NB 196  // ceil(N_NODES/256)

__device__ __forceinline__ unsigned short f2bf(float f) {
    unsigned u = __float_as_uint(f);
    return (unsigned short)((u + 0x7FFF + ((u >> 16) & 1)) >> 16);  // RNE
}

// ---------------- degree ----------------
__global__ void k_deg(const int* __restrict__ dst, int* __restrict__ deg) {
    int e = blockIdx.x * blockDim.x + threadIdx.x;
    if (e < N_EDGES) atomicAdd(&deg[dst[e]], 1);
}

// ---------------- graph starts via binary search (batch is sorted) ----------------
__global__ void k_starts(const int* __restrict__ batch, int* __restrict__ starts) {
    int g = blockIdx.x * blockDim.x + threadIdx.x;
    if (g > N_GRAPHS) return;
    int lo = 0, hi = N_NODES;
    while (lo < hi) { int mid = (lo + hi) >> 1; if (batch[mid] < g) lo = mid + 1; else hi = mid; }
    starts[g] = lo;
}

// ---------------- 3-phase multi-block scan ----------------
__global__ __launch_bounds__(256) void kb_sum(const int* __restrict__ deg,
                                              int* __restrict__ bsum) {
    int i = blockIdx.x * 256 + threadIdx.x;
    int v = (i < N_NODES) ? deg[i] : 0;
    #pragma unroll
    for (int m = 1; m < 64; m <<= 1) v += __shfl_xor(v, m, 64);
    __shared__ int ws[4];
    int lane = threadIdx.x & 63, w = threadIdx.x >> 6;
    if (lane == 0) ws[w] = v;
    __syncthreads();
    if (threadIdx.x == 0) bsum[blockIdx.x] = ws[0] + ws[1] + ws[2] + ws[3];
}

__global__ __launch_bounds__(256) void kb_scan(const int* __restrict__ bsum,
                                               int* __restrict__ bofs,
                                               int* __restrict__ rowstart) {
    int t = threadIdx.x, lane = t & 63, w = t >> 6;
    int v = (t < NB) ? bsum[t] : 0;
    int incl = v;
    #pragma unroll
    for (int off = 1; off < 64; off <<= 1) {
        int u = __shfl_up(incl, off, 64);
        if (lane >= off) incl += u;
    }
    __shared__ int ws[4];
    if (lane == 63) ws[w] = incl;
    __syncthreads();
    int add = 0;
    for (int k = 0; k < w; k++) add += ws[k];
    incl += add;
    if (t < NB) bofs[t] = incl - v;
    if (t == 255) rowstart[N_NODES] = incl;
}

__global__ __launch_bounds__(256) void kb_emit(const int* __restrict__ deg,
                                               const int* __restrict__ bofs,
                                               const int* __restrict__ x,
                                               int* __restrict__ rowstart,
                                               float* __restrict__ dinv,
                                               int2* __restrict__ xd) {
    int b = blockIdx.x, t = threadIdx.x, i = b * 256 + t;
    int lane = t & 63, w = t >> 6;
    int v = (i < N_NODES) ? deg[i] : 0;
    int incl = v;
    #pragma unroll
    for (int off = 1; off < 64; off <<= 1) {
        int u = __shfl_up(incl, off, 64);
        if (lane >= off) incl += u;
    }
    __shared__ int ws[4];
    if (lane == 63) ws[w] = incl;
    __syncthreads();
    int add = bofs[b];
    for (int k = 0; k < w; k++) add += ws[k];
    if (i < N_NODES) {
        rowstart[i] = add + incl - v;
        float dv = rsqrtf((float)v + 1.0f);
        dinv[i] = dv;
        xd[i] = make_int2(x[i], __float_as_int(dv));
    }
}

// ---------------- CSR scatter (4 B per edge) ----------------
__global__ void k_scatter(const int* __restrict__ src, const int* __restrict__ dst,
                          const int* __restrict__ rowstart, int* __restrict__ cursor,
                          int* __restrict__ csr_src) {
    int e = blockIdx.x * blockDim.x + threadIdx.x;
    if (e >= N_EDGES) return;
    int d = dst[e];
    int pos = rowstart[d] + atomicAdd(&cursor[d], 1);
    csr_src[pos] = src[e];
}

// ---------------- EW1 = emb @ W1 (tiny: 100x128) ----------------
__global__ void k_ew1(const float* __restrict__ emb, const float* __restrict__ W1,
                      float* __restrict__ EW1) {
    int idx = blockIdx.x * blockDim.x + threadIdx.x;
    if (idx >= VOCAB * DIM) return;
    int r = idx >> 7, c = idx & 127;
    float acc = 0.f;
    for (int k = 0; k < DIM; k++) acc += emb[r * DIM + k] * W1[k * DIM + c];
    EW1[idx] = acc;
}

// ---------------- layer-1 agg + LN + ReLU (EW1 in LDS, chunked broadcast) ----------------
__global__ __launch_bounds__(256) void k_agg1(
    const float* __restrict__ EW1, const int2* __restrict__ xd,
    const int* __restrict__ rowstart, const int* __restrict__ csr_src,
    const float* __restrict__ b1, const float* __restrict__ g1,
    const float* __restrict__ be1, float2* __restrict__ h1) {
    __shared__ float2 ew[VOCAB * 64];  // 51200 B
    for (int idx = threadIdx.x; idx < VOCAB * 64; idx += blockDim.x)
        ew[idx] = ((const float2*)EW1)[idx];
    __syncthreads();
    int lane = threadIdx.x & 63;
    int wave = (blockIdx.x * blockDim.x + threadIdx.x) >> 6;
    int nw = (gridDim.x * blockDim.x) >> 6;
    float2 bb = make_float2(b1[2 * lane], b1[2 * lane + 1]);
    float2 gg = make_float2(g1[2 * lane], g1[2 * lane + 1]);
    float2 eb = make_float2(be1[2 * lane], be1[2 * lane + 1]);
    for (int i = wave; i < N_NODES; i += nw) {
        int2 self = xd[i];
        float di = __int_as_float(self.y);
        float2 e0 = ew[self.x * 64 + lane];
        float ax = di * e0.x, ay = di * e0.y;  // self-loop: dinv_i * EW1[x_i]
        int p = rowstart[i], pe = rowstart[i + 1];
        while (p < pe) {
            int n = pe - p; if (n > 64) n = 64;
            int2 my = make_int2(0, 0);
            if (lane < n) { int s = csr_src[p + lane]; my = xd[s]; }
            int j = 0;
            for (; j + 8 <= n; j += 8) {
                #pragma unroll
                for (int u = 0; u < 8; u++) {
                    int xv = __shfl(my.x, j + u, 64);
                    float ds = __int_as_float(__shfl(my.y, j + u, 64));
                    float2 es = ew[xv * 64 + lane];
                    ax += ds * es.x; ay += ds * es.y;
                }
            }
            for (; j < n; j++) {
                int xv = __shfl(my.x, j, 64);
                float ds = __int_as_float(__shfl(my.y, j, 64));
                float2 es = ew[xv * 64 + lane];
                ax += ds * es.x; ay += ds * es.y;
            }
            p += n;
        }
        float a0 = di * ax + bb.x, a1 = di * ay + bb.y;
        float s = a0 + a1;
        #pragma unroll
        for (int m = 1; m < 64; m <<= 1) s += __shfl_xor(s, m, 64);
        float mu = s * (1.f / 128.f);
        float d0 = a0 - mu, d1 = a1 - mu;
        float q = d0 * d0 + d1 * d1;
        #pragma unroll
        for (int m = 1; m < 64; m <<= 1) q += __shfl_xor(q, m, 64);
        float r = rsqrtf(q * (1.f / 128.f) + LN_EPS);
        float o0 = fmaxf(d0 * r * gg.x + eb.x, 0.f);
        float o1 = fmaxf(d1 * r * gg.y + eb.y, 0.f);
        h1[i * 64 + lane] = make_float2(o0, o1);
    }
}

// ---------------- v2 = bf16( dinv * (h1 @ W2) ) ----------------
// 512 threads, 128 rows/block. Thread = 4 rows x 8 cols register tile (32 acc).
// Per k: 4 b32 a-reads (2-way bank alias, free) + 2 b128 W2 reads = 1.5 B/MAC
// of LDS traffic (was 4.25). 8 waves/block for latency hiding.
#define AW 132  // A-tile stride: (4ty)*132 banks alternate {0,16} -> 2-way, free
__global__ __launch_bounds__(512) void k_mm2(
    const float* __restrict__ h1, const float* __restrict__ W2,
    const float* __restrict__ dinv, unsigned short* __restrict__ v2b) {
    __shared__ float w[DIM * DIM];    // 65536 B
    __shared__ float at[128 * AW];    // 67584 B (total 133 KB <= 160 KB)
    int t = threadIdx.x;
    for (int idx = t * 4; idx < DIM * DIM; idx += 2048)
        *(float4*)&w[idx] = *(const float4*)&W2[idx];
    int row0 = blockIdx.x * 128;
    for (int idx = t * 4; idx < 128 * DIM; idx += 2048) {
        int r = idx >> 7, c = idx & 127;
        int row = row0 + r;
        float4 val = make_float4(0.f, 0.f, 0.f, 0.f);
        if (row < N_NODES) val = *(const float4*)&h1[(size_t)row * DIM + c];
        *(float4*)&at[r * AW + c] = val;
    }
    __syncthreads();
    int tx = t & 15;   // 8 cols each
    int ty = t >> 4;   // 4 rows each
    float4 acc[4][2];
    #pragma unroll
    for (int r = 0; r < 4; r++) {
        acc[r][0] = make_float4(0.f, 0.f, 0.f, 0.f);
        acc[r][1] = make_float4(0.f, 0.f, 0.f, 0.f);
    }
    const float* arow = &at[(4 * ty) * AW];
    const float* wcol = &w[tx * 8];
    #pragma unroll 4
    for (int k = 0; k < DIM; k++) {
        float a0 = arow[k];
        float a1 = arow[AW + k];
        float a2 = arow[2 * AW + k];
        float a3 = arow[3 * AW + k];
        float4 w0 = *(const float4*)&wcol[k * DIM];
        float4 w1 = *(const float4*)&wcol[k * DIM + 4];
        acc[0][0].x += a0 * w0.x; acc[0][0].y += a0 * w0.y; acc[0][0].z += a0 * w0.z; acc[0][0].w += a0 * w0.w;
        acc[0][1].x += a0 * w1.x; acc[0][1].y += a0 * w1.y; acc[0][1].z += a0 * w1.z; acc[0][1].w += a0 * w1.w;
        acc[1][0].x += a1 * w0.x; acc[1][0].y += a1 * w0.y; acc[1][0].z += a1 * w0.z; acc[1][0].w += a1 * w0.w;
        acc[1][1].x += a1 * w1.x; acc[1][1].y += a1 * w1.y; acc[1][1].z += a1 * w1.z; acc[1][1].w += a1 * w1.w;
        acc[2][0].x += a2 * w0.x; acc[2][0].y += a2 * w0.y; acc[2][0].z += a2 * w0.z; acc[2][0].w += a2 * w0.w;
        acc[2][1].x += a2 * w1.x; acc[2][1].y += a2 * w1.y; acc[2][1].z += a2 * w1.z; acc[2][1].w += a2 * w1.w;
        acc[3][0].x += a3 * w0.x; acc[3][0].y += a3 * w0.y; acc[3][0].z += a3 * w0.z; acc[3][0].w += a3 * w0.w;
        acc[3][1].x += a3 * w1.x; acc[3][1].y += a3 * w1.y; acc[3][1].z += a3 * w1.z; acc[3][1].w += a3 * w1.w;
    }
    #pragma unroll
    for (int r = 0; r < 4; r++) {
        int row = row0 + 4 * ty + r;
        if (row >= N_NODES) break;
        float di = dinv[row];
        uint4 pk;
        pk.x = (unsigned)f2bf(di * acc[r][0].x) | ((unsigned)f2bf(di * acc[r][0].y) << 16);
        pk.y = (unsigned)f2bf(di * acc[r][0].z) | ((unsigned)f2bf(di * acc[r][0].w) << 16);
        pk.z = (unsigned)f2bf(di * acc[r][1].x) | ((unsigned)f2bf(di * acc[r][1].y) << 16);
        pk.w = (unsigned)f2bf(di * acc[r][1].z) | ((unsigned)f2bf(di * acc[r][1].w) << 16);
        *(uint4*)&v2b[(size_t)row * DIM + tx * 8] = pk;
    }
}

// ---------------- layer-2 agg (bf16 gathers) + LN + ReLU + fused pool sums ----------------
__global__ __launch_bounds__(256) void k_agg2(
    const unsigned* __restrict__ v2u, const float* __restrict__ dinv,
    const int* __restrict__ rowstart, const int* __restrict__ csr_src,
    const int* __restrict__ batch,
    const float* __restrict__ b2, const float* __restrict__ g2,
    const float* __restrict__ be2, float* __restrict__ pooled) {
    int lane = threadIdx.x & 63;
    int wave = (blockIdx.x * blockDim.x + threadIdx.x) >> 6;
    int nw = (gridDim.x * blockDim.x) >> 6;
    float2 bb = make_float2(b2[2 * lane], b2[2 * lane + 1]);
    float2 gg = make_float2(g2[2 * lane], g2[2 * lane + 1]);
    float2 eb = make_float2(be2[2 * lane], be2[2 * lane + 1]);
    for (int i = wave; i < N_NODES; i += nw) {
        float di = dinv[i];
        unsigned u0 = v2u[i * 64 + lane];  // self term (dinv_i*hW_i folded in v2)
        float ax = __uint_as_float(u0 << 16);
        float ay = __uint_as_float(u0 & 0xFFFF0000u);
        int p = rowstart[i], pe = rowstart[i + 1];
        while (p < pe) {
            int n = pe - p; if (n > 64) n = 64;
            int mys = 0;
            if (lane < n) mys = csr_src[p + lane];
            int j = 0;
            for (; j + 8 <= n; j += 8) {
                #pragma unroll
                for (int u = 0; u < 8; u++) {
                    int s = __shfl(mys, j + u, 64);
                    unsigned uv = v2u[s * 64 + lane];
                    ax += __uint_as_float(uv << 16);
                    ay += __uint_as_float(uv & 0xFFFF0000u);
                }
            }
            for (; j < n; j++) {
                int s = __shfl(mys, j, 64);
                unsigned uv = v2u[s * 64 + lane];
                ax += __uint_as_float(uv << 16);
                ay += __uint_as_float(uv & 0xFFFF0000u);
            }
            p += n;
        }
        float a0 = di * ax + bb.x, a1 = di * ay + bb.y;
        float s = a0 + a1;
        #pragma unroll
        for (int m = 1; m < 64; m <<= 1) s += __shfl_xor(s, m, 64);
        float mu = s * (1.f / 128.f);
        float d0 = a0 - mu, d1 = a1 - mu;
        float q = d0 * d0 + d1 * d1;
        #pragma unroll
        for (int m = 1; m < 64; m <<= 1) q += __shfl_xor(q, m, 64);
        float r = rsqrtf(q * (1.f / 128.f) + LN_EPS);
        float o0 = fmaxf(d0 * r * gg.x + eb.x, 0.f);
        float o1 = fmaxf(d1 * r * gg.y + eb.y, 0.f);
        int g = batch[i];
        atomicAdd(&pooled[g * DIM + 2 * lane], o0);
        atomicAdd(&pooled[g * DIM + 2 * lane + 1], o1);
    }
}

// ---------------- out[g] = pooled[g].fcW / max(cnt,1) + fcb ----------------
__global__ void k_out(const float* __restrict__ pooled, const int* __restrict__ starts,
                      const float* __restrict__ fcW, const float* __restrict__ fcb,
                      float* __restrict__ out) {
    int lane = threadIdx.x & 63;
    int g = (blockIdx.x * blockDim.x + threadIdx.x) >> 6;
    if (g >= N_GRAPHS) return;
    float2 p = ((const float2*)pooled)[g * 64 + lane];
    float2 w = ((const float2*)fcW)[lane];
    float s = p.x * w.x + p.y * w.y;
    #pragma unroll
    for (int m = 1; m < 64; m <<= 1) s += __shfl_xor(s, m, 64);
    if (lane == 0) {
        float c = (float)(starts[g + 1] - starts[g]);
        if (c < 1.f) c = 1.f;
        out[g] = s / c + fcb[0];
    }
}

extern "C" void kernel_launch(void* const* d_in, const int* in_sizes, int n_in,
                              void* d_out, int out_size, void* d_ws, size_t ws_size,
                              hipStream_t stream) {
    (void)in_sizes; (void)n_in; (void)out_size; (void)ws_size;
    const int* x    = (const int*)d_in[0];
    const int* src  = (const int*)d_in[1];
    const int* dst  = src + N_EDGES;
    const int* batch = (const int*)d_in[2];
    const float* emb = (const float*)d_in[3];
    const float* W1  = (const float*)d_in[4];
    const float* b1  = (const float*)d_in[5];
    const float* g1  = (const float*)d_in[6];
    const float* be1 = (const float*)d_in[7];
    const float* W2  = (const float*)d_in[8];
    const float* b2  = (const float*)d_in[9];
    const float* g2  = (const float*)d_in[10];
    const float* be2 = (const float*)d_in[11];
    const float* fcW = (const float*)d_in[12];
    const float* fcb = (const float*)d_in[13];
    float* out = (float*)d_out;

    char* wsp = (char*)d_ws;
    size_t off = 0;
    auto alloc = [&](size_t bytes) -> void* {
        void* p = wsp + off;
        off += (bytes + 15) & ~(size_t)15;
        return p;
    };
    // ---- zeroed region ----
    int*   deg      = (int*)alloc(N_NODES * 4);
    int*   cursor   = (int*)alloc(N_NODES * 4);
    float* pooled   = (float*)alloc(N_GRAPHS * DIM * 4);
    size_t zero_bytes = off;
    // ---- scratch ----
    int*   rowstart = (int*)alloc((N_NODES + 1) * 4);
    float* dinv     = (float*)alloc(N_NODES * 4);
    int2*  xd       = (int2*)alloc((size_t)N_NODES * 8);
    int*   csr_src  = (int*)alloc(N_EDGES * 4);
    float* EW1      = (float*)alloc(VOCAB * DIM * 4);
    int*   starts   = (int*)alloc((N_GRAPHS + 1) * 4);
    int*   bsum     = (int*)alloc(NB * 4);
    int*   bofs     = (int*)alloc(NB * 4);
    float* h1       = (float*)alloc((size_t)N_NODES * DIM * 4);
    unsigned short* v2b = (unsigned short*)alloc((size_t)N_NODES * DIM * 2);

    hipMemsetAsync(d_ws, 0, zero_bytes, stream);

    k_deg<<<(N_EDGES + 255) / 256, 256, 0, stream>>>(dst, deg);
    k_starts<<<3, 256, 0, stream>>>(batch, starts);
    kb_sum<<<NB, 256, 0, stream>>>(deg, bsum);
    kb_scan<<<1, 256, 0, stream>>>(bsum, bofs, rowstart);
    kb_emit<<<NB, 256, 0, stream>>>(deg, bofs, x, rowstart, dinv, xd);
    k_scatter<<<(N_EDGES + 255) / 256, 256, 0, stream>>>(src, dst, rowstart, cursor, csr_src);
    k_ew1<<<(VOCAB * DIM + 255) / 256, 256, 0, stream>>>(emb, W1, EW1);
    // 768 blocks = 3 blocks/CU (LDS-capped), no scheduling tail
    k_agg1<<<768, 256, 0, stream>>>(EW1, xd, rowstart, csr_src, b1, g1, be1, (float2*)h1);
    k_mm2<<<(N_NODES + 127) / 128, 512, 0, stream>>>(h1, W2, dinv, v2b);
    k_agg2<<<2048, 256, 0, stream>>>((const unsigned*)v2b, dinv, rowstart, csr_src, batch,
                                     b2, g2, be2, pooled);
    k_out<<<(N_GRAPHS * 64 + 255) / 256, 256, 0, stream>>>(pooled, starts, fcW, fcb, out);
}

// Round 6
// 308.423 us; speedup vs baseline: 1.7165x; 1.0576x over previous
//
#include <hip/hip_runtime.h>
#include <math.h>

#define N_NODES 50000
#define N_EDGES 800000
#define VOCAB 100
#define DIM 128
#define N_GRAPHS 512
#define LN_EPS 1e-5f
#define NB 196   // ceil(N_NODES/256)
#define SEG 8    // nodes per wave in k_agg2

__device__ __forceinline__ unsigned short f2bf(float f) {
    unsigned u = __float_as_uint(f);
    return (unsigned short)((u + 0x7FFF + ((u >> 16) & 1)) >> 16);  // RNE
}

// ---------------- degree ----------------
__global__ void k_deg(const int* __restrict__ dst, int* __restrict__ deg) {
    int e = blockIdx.x * blockDim.x + threadIdx.x;
    if (e < N_EDGES) atomicAdd(&deg[dst[e]], 1);
}

// ---------------- graph starts via binary search (batch is sorted) ----------------
__global__ void k_starts(const int* __restrict__ batch, int* __restrict__ starts) {
    int g = blockIdx.x * blockDim.x + threadIdx.x;
    if (g > N_GRAPHS) return;
    int lo = 0, hi = N_NODES;
    while (lo < hi) { int mid = (lo + hi) >> 1; if (batch[mid] < g) lo = mid + 1; else hi = mid; }
    starts[g] = lo;
}

// ---------------- 3-phase multi-block scan ----------------
__global__ __launch_bounds__(256) void kb_sum(const int* __restrict__ deg,
                                              int* __restrict__ bsum) {
    int i = blockIdx.x * 256 + threadIdx.x;
    int v = (i < N_NODES) ? deg[i] : 0;
    #pragma unroll
    for (int m = 1; m < 64; m <<= 1) v += __shfl_xor(v, m, 64);
    __shared__ int ws[4];
    int lane = threadIdx.x & 63, w = threadIdx.x >> 6;
    if (lane == 0) ws[w] = v;
    __syncthreads();
    if (threadIdx.x == 0) bsum[blockIdx.x] = ws[0] + ws[1] + ws[2] + ws[3];
}

__global__ __launch_bounds__(256) void kb_scan(const int* __restrict__ bsum,
                                               int* __restrict__ bofs,
                                               int* __restrict__ rowstart) {
    int t = threadIdx.x, lane = t & 63, w = t >> 6;
    int v = (t < NB) ? bsum[t] : 0;
    int incl = v;
    #pragma unroll
    for (int off = 1; off < 64; off <<= 1) {
        int u = __shfl_up(incl, off, 64);
        if (lane >= off) incl += u;
    }
    __shared__ int ws[4];
    if (lane == 63) ws[w] = incl;
    __syncthreads();
    int add = 0;
    for (int k = 0; k < w; k++) add += ws[k];
    incl += add;
    if (t < NB) bofs[t] = incl - v;
    if (t == 255) rowstart[N_NODES] = incl;
}

__global__ __launch_bounds__(256) void kb_emit(const int* __restrict__ deg,
                                               const int* __restrict__ bofs,
                                               const int* __restrict__ x,
                                               int* __restrict__ rowstart,
                                               float* __restrict__ dinv,
                                               int2* __restrict__ xd) {
    int b = blockIdx.x, t = threadIdx.x, i = b * 256 + t;
    int lane = t & 63, w = t >> 6;
    int v = (i < N_NODES) ? deg[i] : 0;
    int incl = v;
    #pragma unroll
    for (int off = 1; off < 64; off <<= 1) {
        int u = __shfl_up(incl, off, 64);
        if (lane >= off) incl += u;
    }
    __shared__ int ws[4];
    if (lane == 63) ws[w] = incl;
    __syncthreads();
    int add = bofs[b];
    for (int k = 0; k < w; k++) add += ws[k];
    if (i < N_NODES) {
        rowstart[i] = add + incl - v;
        float dv = rsqrtf((float)v + 1.0f);
        dinv[i] = dv;
        xd[i] = make_int2(x[i], __float_as_int(dv));
    }
}

// ---------------- CSR scatter (4 B per edge) ----------------
__global__ void k_scatter(const int* __restrict__ src, const int* __restrict__ dst,
                          const int* __restrict__ rowstart, int* __restrict__ cursor,
                          int* __restrict__ csr_src) {
    int e = blockIdx.x * blockDim.x + threadIdx.x;
    if (e >= N_EDGES) return;
    int d = dst[e];
    int pos = rowstart[d] + atomicAdd(&cursor[d], 1);
    csr_src[pos] = src[e];
}

// ---------------- EW1 = emb @ W1 (tiny: 100x128) ----------------
__global__ void k_ew1(const float* __restrict__ emb, const float* __restrict__ W1,
                      float* __restrict__ EW1) {
    int idx = blockIdx.x * blockDim.x + threadIdx.x;
    if (idx >= VOCAB * DIM) return;
    int r = idx >> 7, c = idx & 127;
    float acc = 0.f;
    for (int k = 0; k < DIM; k++) acc += emb[r * DIM + k] * W1[k * DIM + c];
    EW1[idx] = acc;
}

// ---------------- layer-1 agg + LN + ReLU (EW1 in LDS, chunked broadcast) ----------------
__global__ __launch_bounds__(256) void k_agg1(
    const float* __restrict__ EW1, const int2* __restrict__ xd,
    const int* __restrict__ rowstart, const int* __restrict__ csr_src,
    const float* __restrict__ b1, const float* __restrict__ g1,
    const float* __restrict__ be1, float2* __restrict__ h1) {
    __shared__ float2 ew[VOCAB * 64];  // 51200 B
    for (int idx = threadIdx.x; idx < VOCAB * 64; idx += blockDim.x)
        ew[idx] = ((const float2*)EW1)[idx];
    __syncthreads();
    int lane = threadIdx.x & 63;
    int wave = (blockIdx.x * blockDim.x + threadIdx.x) >> 6;
    int nw = (gridDim.x * blockDim.x) >> 6;
    float2 bb = make_float2(b1[2 * lane], b1[2 * lane + 1]);
    float2 gg = make_float2(g1[2 * lane], g1[2 * lane + 1]);
    float2 eb = make_float2(be1[2 * lane], be1[2 * lane + 1]);
    for (int i = wave; i < N_NODES; i += nw) {
        int2 self = xd[i];
        float di = __int_as_float(self.y);
        float2 e0 = ew[self.x * 64 + lane];
        float ax = di * e0.x, ay = di * e0.y;  // self-loop: dinv_i * EW1[x_i]
        int p = rowstart[i], pe = rowstart[i + 1];
        while (p < pe) {
            int n = pe - p; if (n > 64) n = 64;
            int2 my = make_int2(0, 0);
            if (lane < n) { int s = csr_src[p + lane]; my = xd[s]; }
            int j = 0;
            for (; j + 8 <= n; j += 8) {
                #pragma unroll
                for (int u = 0; u < 8; u++) {
                    int xv = __shfl(my.x, j + u, 64);
                    float ds = __int_as_float(__shfl(my.y, j + u, 64));
                    float2 es = ew[xv * 64 + lane];
                    ax += ds * es.x; ay += ds * es.y;
                }
            }
            for (; j < n; j++) {
                int xv = __shfl(my.x, j, 64);
                float ds = __int_as_float(__shfl(my.y, j, 64));
                float2 es = ew[xv * 64 + lane];
                ax += ds * es.x; ay += ds * es.y;
            }
            p += n;
        }
        float a0 = di * ax + bb.x, a1 = di * ay + bb.y;
        float s = a0 + a1;
        #pragma unroll
        for (int m = 1; m < 64; m <<= 1) s += __shfl_xor(s, m, 64);
        float mu = s * (1.f / 128.f);
        float d0 = a0 - mu, d1 = a1 - mu;
        float q = d0 * d0 + d1 * d1;
        #pragma unroll
        for (int m = 1; m < 64; m <<= 1) q += __shfl_xor(q, m, 64);
        float r = rsqrtf(q * (1.f / 128.f) + LN_EPS);
        float o0 = fmaxf(d0 * r * gg.x + eb.x, 0.f);
        float o1 = fmaxf(d1 * r * gg.y + eb.y, 0.f);
        h1[i * 64 + lane] = make_float2(o0, o1);
    }
}

// ---------------- v2 = bf16( dinv * (h1 @ W2) ) ----------------
#define AW 132
__global__ __launch_bounds__(512) void k_mm2(
    const float* __restrict__ h1, const float* __restrict__ W2,
    const float* __restrict__ dinv, unsigned short* __restrict__ v2b) {
    __shared__ float w[DIM * DIM];    // 65536 B
    __shared__ float at[128 * AW];    // 67584 B
    int t = threadIdx.x;
    for (int idx = t * 4; idx < DIM * DIM; idx += 2048)
        *(float4*)&w[idx] = *(const float4*)&W2[idx];
    int row0 = blockIdx.x * 128;
    for (int idx = t * 4; idx < 128 * DIM; idx += 2048) {
        int r = idx >> 7, c = idx & 127;
        int row = row0 + r;
        float4 val = make_float4(0.f, 0.f, 0.f, 0.f);
        if (row < N_NODES) val = *(const float4*)&h1[(size_t)row * DIM + c];
        *(float4*)&at[r * AW + c] = val;
    }
    __syncthreads();
    int tx = t & 15;
    int ty = t >> 4;
    float4 acc[4][2];
    #pragma unroll
    for (int r = 0; r < 4; r++) {
        acc[r][0] = make_float4(0.f, 0.f, 0.f, 0.f);
        acc[r][1] = make_float4(0.f, 0.f, 0.f, 0.f);
    }
    const float* arow = &at[(4 * ty) * AW];
    const float* wcol = &w[tx * 8];
    #pragma unroll 4
    for (int k = 0; k < DIM; k++) {
        float a0 = arow[k];
        float a1 = arow[AW + k];
        float a2 = arow[2 * AW + k];
        float a3 = arow[3 * AW + k];
        float4 w0 = *(const float4*)&wcol[k * DIM];
        float4 w1 = *(const float4*)&wcol[k * DIM + 4];
        acc[0][0].x += a0 * w0.x; acc[0][0].y += a0 * w0.y; acc[0][0].z += a0 * w0.z; acc[0][0].w += a0 * w0.w;
        acc[0][1].x += a0 * w1.x; acc[0][1].y += a0 * w1.y; acc[0][1].z += a0 * w1.z; acc[0][1].w += a0 * w1.w;
        acc[1][0].x += a1 * w0.x; acc[1][0].y += a1 * w0.y; acc[1][0].z += a1 * w0.z; acc[1][0].w += a1 * w0.w;
        acc[1][1].x += a1 * w1.x; acc[1][1].y += a1 * w1.y; acc[1][1].z += a1 * w1.z; acc[1][1].w += a1 * w1.w;
        acc[2][0].x += a2 * w0.x; acc[2][0].y += a2 * w0.y; acc[2][0].z += a2 * w0.z; acc[2][0].w += a2 * w0.w;
        acc[2][1].x += a2 * w1.x; acc[2][1].y += a2 * w1.y; acc[2][1].z += a2 * w1.z; acc[2][1].w += a2 * w1.w;
        acc[3][0].x += a3 * w0.x; acc[3][0].y += a3 * w0.y; acc[3][0].z += a3 * w0.z; acc[3][0].w += a3 * w0.w;
        acc[3][1].x += a3 * w1.x; acc[3][1].y += a3 * w1.y; acc[3][1].z += a3 * w1.z; acc[3][1].w += a3 * w1.w;
    }
    #pragma unroll
    for (int r = 0; r < 4; r++) {
        int row = row0 + 4 * ty + r;
        if (row >= N_NODES) break;
        float di = dinv[row];
        uint4 pk;
        pk.x = (unsigned)f2bf(di * acc[r][0].x) | ((unsigned)f2bf(di * acc[r][0].y) << 16);
        pk.y = (unsigned)f2bf(di * acc[r][0].z) | ((unsigned)f2bf(di * acc[r][0].w) << 16);
        pk.z = (unsigned)f2bf(di * acc[r][1].x) | ((unsigned)f2bf(di * acc[r][1].y) << 16);
        pk.w = (unsigned)f2bf(di * acc[r][1].z) | ((unsigned)f2bf(di * acc[r][1].w) << 16);
        *(uint4*)&v2b[(size_t)row * DIM + tx * 8] = pk;
    }
}

// ---------------- layer-2 agg: contiguous segments, dual-buffered csr chunks,
// register pool accumulation with boundary flush ----------------
__global__ __launch_bounds__(256) void k_agg2(
    const unsigned* __restrict__ v2u, const float* __restrict__ dinv,
    const int* __restrict__ rowstart, const int* __restrict__ csr_src,
    const int* __restrict__ batch,
    const float* __restrict__ b2, const float* __restrict__ g2,
    const float* __restrict__ be2, float* __restrict__ pooled) {
    int lane = threadIdx.x & 63;
    int wave = (blockIdx.x * blockDim.x + threadIdx.x) >> 6;
    int i0 = wave * SEG;
    if (i0 >= N_NODES) return;
    int i1 = i0 + SEG; if (i1 > N_NODES) i1 = N_NODES;
    int nseg = i1 - i0;

    float2 bb = make_float2(b2[2 * lane], b2[2 * lane + 1]);
    float2 gg = make_float2(g2[2 * lane], g2[2 * lane + 1]);
    float2 eb = make_float2(be2[2 * lane], be2[2 * lane + 1]);

    // segment preloads: rowstart[i0..i1], dinv[i0..i1), batch[i0..i1)
    int rsv = 0;
    if (lane <= nseg) rsv = rowstart[i0 + lane];
    float dv = 0.f; int bv = 0;
    if (lane < nseg) { dv = dinv[i0 + lane]; bv = batch[i0 + lane]; }

    int base = __shfl(rsv, 0, 64);
    int segend = __shfl(rsv, nseg, 64);

    // dual-buffered 64-edge csr chunks
    int p0 = base;
    int buf0 = (base + lane < segend) ? csr_src[base + lane] : 0;
    int buf1 = (base + 64 + lane < segend) ? csr_src[base + 64 + lane] : 0;

    float px = 0.f, py = 0.f;
    int cur_g = __shfl(bv, 0, 64);
    int rs = base;
    for (int i = i0; i < i1; i++) {
        int k = i - i0;
        int re = __shfl(rsv, k + 1, 64);
        float di = __shfl(dv, k, 64);
        int g = __shfl(bv, k, 64);
        unsigned u0 = v2u[(size_t)i * 64 + lane];  // self term (dinv_i*hW_i folded)
        float ax = __uint_as_float(u0 << 16);
        float ay = __uint_as_float(u0 & 0xFFFF0000u);
        int e = rs;
        while (e < re) {
            int off = e - p0;
            if (off >= 64) {  // uniform, rare: advance chunk window
                p0 += 64;
                buf0 = buf1;
                buf1 = (p0 + 64 + lane < segend) ? csr_src[p0 + 64 + lane] : 0;
                off -= 64;
            }
            int n = re - e;
            int avail = 64 - off;
            if (n > avail) n = avail;
            int j = 0;
            for (; j + 8 <= n; j += 8) {
                #pragma unroll
                for (int u = 0; u < 8; u++) {
                    int s = __shfl(buf0, off + j + u, 64);
                    unsigned uv = v2u[(size_t)s * 64 + lane];
                    ax += __uint_as_float(uv << 16);
                    ay += __uint_as_float(uv & 0xFFFF0000u);
                }
            }
            for (; j < n; j++) {
                int s = __shfl(buf0, off + j, 64);
                unsigned uv = v2u[(size_t)s * 64 + lane];
                ax += __uint_as_float(uv << 16);
                ay += __uint_as_float(uv & 0xFFFF0000u);
            }
            e += n;
        }
        rs = re;
        float a0 = di * ax + bb.x, a1 = di * ay + bb.y;
        float s = a0 + a1;
        #pragma unroll
        for (int m = 1; m < 64; m <<= 1) s += __shfl_xor(s, m, 64);
        float mu = s * (1.f / 128.f);
        float d0 = a0 - mu, d1 = a1 - mu;
        float q = d0 * d0 + d1 * d1;
        #pragma unroll
        for (int m = 1; m < 64; m <<= 1) q += __shfl_xor(q, m, 64);
        float r = rsqrtf(q * (1.f / 128.f) + LN_EPS);
        float o0 = fmaxf(d0 * r * gg.x + eb.x, 0.f);
        float o1 = fmaxf(d1 * r * gg.y + eb.y, 0.f);
        if (g != cur_g) {  // uniform: flush accumulated pool sums
            atomicAdd(&pooled[cur_g * DIM + 2 * lane], px);
            atomicAdd(&pooled[cur_g * DIM + 2 * lane + 1], py);
            px = 0.f; py = 0.f; cur_g = g;
        }
        px += o0; py += o1;
    }
    atomicAdd(&pooled[cur_g * DIM + 2 * lane], px);
    atomicAdd(&pooled[cur_g * DIM + 2 * lane + 1], py);
}

// ---------------- out[g] = pooled[g].fcW / max(cnt,1) + fcb ----------------
__global__ void k_out(const float* __restrict__ pooled, const int* __restrict__ starts,
                      const float* __restrict__ fcW, const float* __restrict__ fcb,
                      float* __restrict__ out) {
    int lane = threadIdx.x & 63;
    int g = (blockIdx.x * blockDim.x + threadIdx.x) >> 6;
    if (g >= N_GRAPHS) return;
    float2 p = ((const float2*)pooled)[g * 64 + lane];
    float2 w = ((const float2*)fcW)[lane];
    float s = p.x * w.x + p.y * w.y;
    #pragma unroll
    for (int m = 1; m < 64; m <<= 1) s += __shfl_xor(s, m, 64);
    if (lane == 0) {
        float c = (float)(starts[g + 1] - starts[g]);
        if (c < 1.f) c = 1.f;
        out[g] = s / c + fcb[0];
    }
}

extern "C" void kernel_launch(void* const* d_in, const int* in_sizes, int n_in,
                              void* d_out, int out_size, void* d_ws, size_t ws_size,
                              hipStream_t stream) {
    (void)in_sizes; (void)n_in; (void)out_size; (void)ws_size;
    const int* x    = (const int*)d_in[0];
    const int* src  = (const int*)d_in[1];
    const int* dst  = src + N_EDGES;
    const int* batch = (const int*)d_in[2];
    const float* emb = (const float*)d_in[3];
    const float* W1  = (const float*)d_in[4];
    const float* b1  = (const float*)d_in[5];
    const float* g1  = (const float*)d_in[6];
    const float* be1 = (const float*)d_in[7];
    const float* W2  = (const float*)d_in[8];
    const float* b2  = (const float*)d_in[9];
    const float* g2  = (const float*)d_in[10];
    const float* be2 = (const float*)d_in[11];
    const float* fcW = (const float*)d_in[12];
    const float* fcb = (const float*)d_in[13];
    float* out = (float*)d_out;

    char* wsp = (char*)d_ws;
    size_t off = 0;
    auto alloc = [&](size_t bytes) -> void* {
        void* p = wsp + off;
        off += (bytes + 15) & ~(size_t)15;
        return p;
    };
    // ---- zeroed region ----
    int*   deg      = (int*)alloc(N_NODES * 4);
    int*   cursor   = (int*)alloc(N_NODES * 4);
    float* pooled   = (float*)alloc(N_GRAPHS * DIM * 4);
    size_t zero_bytes = off;
    // ---- scratch ----
    int*   rowstart = (int*)alloc((N_NODES + 1) * 4);
    float* dinv     = (float*)alloc(N_NODES * 4);
    int2*  xd       = (int2*)alloc((size_t)N_NODES * 8);
    int*   csr_src  = (int*)alloc(N_EDGES * 4);
    float* EW1      = (float*)alloc(VOCAB * DIM * 4);
    int*   starts   = (int*)alloc((N_GRAPHS + 1) * 4);
    int*   bsum     = (int*)alloc(NB * 4);
    int*   bofs     = (int*)alloc(NB * 4);
    float* h1       = (float*)alloc((size_t)N_NODES * DIM * 4);
    unsigned short* v2b = (unsigned short*)alloc((size_t)N_NODES * DIM * 2);

    hipMemsetAsync(d_ws, 0, zero_bytes, stream);

    k_deg<<<(N_EDGES + 255) / 256, 256, 0, stream>>>(dst, deg);
    k_starts<<<3, 256, 0, stream>>>(batch, starts);
    kb_sum<<<NB, 256, 0, stream>>>(deg, bsum);
    kb_scan<<<1, 256, 0, stream>>>(bsum, bofs, rowstart);
    kb_emit<<<NB, 256, 0, stream>>>(deg, bofs, x, rowstart, dinv, xd);
    k_scatter<<<(N_EDGES + 255) / 256, 256, 0, stream>>>(src, dst, rowstart, cursor, csr_src);
    k_ew1<<<(VOCAB * DIM + 255) / 256, 256, 0, stream>>>(emb, W1, EW1);
    k_agg1<<<768, 256, 0, stream>>>(EW1, xd, rowstart, csr_src, b1, g1, be1, (float2*)h1);
    k_mm2<<<(N_NODES + 127) / 128, 512, 0, stream>>>(h1, W2, dinv, v2b);
    {
        int nwaves = (N_NODES + SEG - 1) / SEG;          // 6250
        int nblocks = (nwaves + 3) / 4;                  // 4 waves/block
        k_agg2<<<nblocks, 256, 0, stream>>>((const unsigned*)v2b, dinv, rowstart, csr_src,
                                            batch, b2, g2, be2, pooled);
    }
    k_out<<<(N_GRAPHS * 64 + 255) / 256, 256, 0, stream>>>(pooled, starts, fcW, fcb, out);
}

// Round 7
// 295.234 us; speedup vs baseline: 1.7932x; 1.0447x over previous
//
#include <hip/hip_runtime.h>
#include <hip/hip_fp16.h>
#include <math.h>

#define N_NODES 50000
#define N_EDGES 800000
#define VOCAB 100
#define DIM 128
#define N_GRAPHS 512
#define LN_EPS 1e-5f
#define NB 196   // ceil(N_NODES/256)
#define SEG 8    // nodes per wave in k_agg2

__device__ __forceinline__ unsigned short f2bf(float f) {
    unsigned u = __float_as_uint(f);
    return (unsigned short)((u + 0x7FFF + ((u >> 16) & 1)) >> 16);  // RNE
}

// ---------------- degree ----------------
__global__ void k_deg(const int* __restrict__ dst, int* __restrict__ deg) {
    int e = blockIdx.x * blockDim.x + threadIdx.x;
    if (e < N_EDGES) atomicAdd(&deg[dst[e]], 1);
}

// ---------------- graph starts via binary search (batch is sorted) ----------------
__global__ void k_starts(const int* __restrict__ batch, int* __restrict__ starts) {
    int g = blockIdx.x * blockDim.x + threadIdx.x;
    if (g > N_GRAPHS) return;
    int lo = 0, hi = N_NODES;
    while (lo < hi) { int mid = (lo + hi) >> 1; if (batch[mid] < g) lo = mid + 1; else hi = mid; }
    starts[g] = lo;
}

// ---------------- 3-phase multi-block scan ----------------
__global__ __launch_bounds__(256) void kb_sum(const int* __restrict__ deg,
                                              int* __restrict__ bsum) {
    int i = blockIdx.x * 256 + threadIdx.x;
    int v = (i < N_NODES) ? deg[i] : 0;
    #pragma unroll
    for (int m = 1; m < 64; m <<= 1) v += __shfl_xor(v, m, 64);
    __shared__ int ws[4];
    int lane = threadIdx.x & 63, w = threadIdx.x >> 6;
    if (lane == 0) ws[w] = v;
    __syncthreads();
    if (threadIdx.x == 0) bsum[blockIdx.x] = ws[0] + ws[1] + ws[2] + ws[3];
}

__global__ __launch_bounds__(256) void kb_scan(const int* __restrict__ bsum,
                                               int* __restrict__ bofs,
                                               int* __restrict__ rowstart) {
    int t = threadIdx.x, lane = t & 63, w = t >> 6;
    int v = (t < NB) ? bsum[t] : 0;
    int incl = v;
    #pragma unroll
    for (int off = 1; off < 64; off <<= 1) {
        int u = __shfl_up(incl, off, 64);
        if (lane >= off) incl += u;
    }
    __shared__ int ws[4];
    if (lane == 63) ws[w] = incl;
    __syncthreads();
    int add = 0;
    for (int k = 0; k < w; k++) add += ws[k];
    incl += add;
    if (t < NB) bofs[t] = incl - v;
    if (t == 255) rowstart[N_NODES] = incl;
}

// emits rowstart, dinv (fp32), and pw[i] = (fp16(dinv_i)<<16) | x_i
__global__ __launch_bounds__(256) void kb_emit(const int* __restrict__ deg,
                                               const int* __restrict__ bofs,
                                               const int* __restrict__ x,
                                               int* __restrict__ rowstart,
                                               float* __restrict__ dinv,
                                               unsigned* __restrict__ pw) {
    int b = blockIdx.x, t = threadIdx.x, i = b * 256 + t;
    int lane = t & 63, w = t >> 6;
    int v = (i < N_NODES) ? deg[i] : 0;
    int incl = v;
    #pragma unroll
    for (int off = 1; off < 64; off <<= 1) {
        int u = __shfl_up(incl, off, 64);
        if (lane >= off) incl += u;
    }
    __shared__ int ws[4];
    if (lane == 63) ws[w] = incl;
    __syncthreads();
    int add = bofs[b];
    for (int k = 0; k < w; k++) add += ws[k];
    if (i < N_NODES) {
        rowstart[i] = add + incl - v;
        float dv = rsqrtf((float)v + 1.0f);
        dinv[i] = dv;
        unsigned hb = (unsigned)__half_as_ushort(__float2half_rn(dv));
        pw[i] = (hb << 16) | (unsigned)x[i];
    }
}

// ---------------- CSR scatter (4 B per edge) ----------------
__global__ void k_scatter(const int* __restrict__ src, const int* __restrict__ dst,
                          const int* __restrict__ rowstart, int* __restrict__ cursor,
                          int* __restrict__ csr_src) {
    int e = blockIdx.x * blockDim.x + threadIdx.x;
    if (e >= N_EDGES) return;
    int d = dst[e];
    int pos = rowstart[d] + atomicAdd(&cursor[d], 1);
    csr_src[pos] = src[e];
}

// ---------------- EW1 = emb @ W1 (tiny: 100x128) ----------------
__global__ void k_ew1(const float* __restrict__ emb, const float* __restrict__ W1,
                      float* __restrict__ EW1) {
    int idx = blockIdx.x * blockDim.x + threadIdx.x;
    if (idx >= VOCAB * DIM) return;
    int r = idx >> 7, c = idx & 127;
    float acc = 0.f;
    for (int k = 0; k < DIM; k++) acc += emb[r * DIM + k] * W1[k * DIM + c];
    EW1[idx] = acc;
}

// ---------------- layer-1 agg + LN + ReLU ----------------
// blockDim 512, grid 768 -> 3 blocks/CU = 24 waves/CU (was 12).
// One shfl per edge: packed (fp16 dinv | x).
__global__ __launch_bounds__(512) void k_agg1(
    const float* __restrict__ EW1, const unsigned* __restrict__ pw,
    const float* __restrict__ dinv,
    const int* __restrict__ rowstart, const int* __restrict__ csr_src,
    const float* __restrict__ b1, const float* __restrict__ g1,
    const float* __restrict__ be1, float2* __restrict__ h1) {
    __shared__ float2 ew[VOCAB * 64];  // 51200 B
    for (int idx = threadIdx.x; idx < VOCAB * 64; idx += blockDim.x)
        ew[idx] = ((const float2*)EW1)[idx];
    __syncthreads();
    int lane = threadIdx.x & 63;
    int wave = (blockIdx.x * blockDim.x + threadIdx.x) >> 6;
    int nw = (gridDim.x * blockDim.x) >> 6;
    float2 bb = make_float2(b1[2 * lane], b1[2 * lane + 1]);
    float2 gg = make_float2(g1[2 * lane], g1[2 * lane + 1]);
    float2 eb = make_float2(be1[2 * lane], be1[2 * lane + 1]);
    for (int i = wave; i < N_NODES; i += nw) {
        float di = dinv[i];
        int xi = (int)(pw[i] & 0xFFFFu);
        float2 e0 = ew[xi * 64 + lane];
        float ax = di * e0.x, ay = di * e0.y;  // self-loop: dinv_i * EW1[x_i] (fp32)
        int p = rowstart[i], pe = rowstart[i + 1];
        while (p < pe) {
            int n = pe - p; if (n > 64) n = 64;
            unsigned myw = 0;
            if (lane < n) myw = pw[csr_src[p + lane]];
            int j = 0;
            for (; j + 8 <= n; j += 8) {
                #pragma unroll
                for (int u = 0; u < 8; u++) {
                    unsigned w = (unsigned)__shfl((int)myw, j + u, 64);
                    int xv = (int)(w & 0xFFFFu);
                    float ds = __half2float(__ushort_as_half((unsigned short)(w >> 16)));
                    float2 es = ew[xv * 64 + lane];
                    ax += ds * es.x; ay += ds * es.y;
                }
            }
            for (; j < n; j++) {
                unsigned w = (unsigned)__shfl((int)myw, j, 64);
                int xv = (int)(w & 0xFFFFu);
                float ds = __half2float(__ushort_as_half((unsigned short)(w >> 16)));
                float2 es = ew[xv * 64 + lane];
                ax += ds * es.x; ay += ds * es.y;
            }
            p += n;
        }
        float a0 = di * ax + bb.x, a1 = di * ay + bb.y;
        float s = a0 + a1;
        #pragma unroll
        for (int m = 1; m < 64; m <<= 1) s += __shfl_xor(s, m, 64);
        float mu = s * (1.f / 128.f);
        float d0 = a0 - mu, d1 = a1 - mu;
        float q = d0 * d0 + d1 * d1;
        #pragma unroll
        for (int m = 1; m < 64; m <<= 1) q += __shfl_xor(q, m, 64);
        float r = rsqrtf(q * (1.f / 128.f) + LN_EPS);
        float o0 = fmaxf(d0 * r * gg.x + eb.x, 0.f);
        float o1 = fmaxf(d1 * r * gg.y + eb.y, 0.f);
        h1[i * 64 + lane] = make_float2(o0, o1);
    }
}

// ---------------- v2 = bf16( dinv * (h1 @ W2) ) ----------------
#define AW 132
__global__ __launch_bounds__(512) void k_mm2(
    const float* __restrict__ h1, const float* __restrict__ W2,
    const float* __restrict__ dinv, unsigned short* __restrict__ v2b) {
    __shared__ float w[DIM * DIM];    // 65536 B
    __shared__ float at[128 * AW];    // 67584 B
    int t = threadIdx.x;
    for (int idx = t * 4; idx < DIM * DIM; idx += 2048)
        *(float4*)&w[idx] = *(const float4*)&W2[idx];
    int row0 = blockIdx.x * 128;
    for (int idx = t * 4; idx < 128 * DIM; idx += 2048) {
        int r = idx >> 7, c = idx & 127;
        int row = row0 + r;
        float4 val = make_float4(0.f, 0.f, 0.f, 0.f);
        if (row < N_NODES) val = *(const float4*)&h1[(size_t)row * DIM + c];
        *(float4*)&at[r * AW + c] = val;
    }
    __syncthreads();
    int tx = t & 15;
    int ty = t >> 4;
    float4 acc[4][2];
    #pragma unroll
    for (int r = 0; r < 4; r++) {
        acc[r][0] = make_float4(0.f, 0.f, 0.f, 0.f);
        acc[r][1] = make_float4(0.f, 0.f, 0.f, 0.f);
    }
    const float* arow = &at[(4 * ty) * AW];
    const float* wcol = &w[tx * 8];
    #pragma unroll 4
    for (int k = 0; k < DIM; k++) {
        float a0 = arow[k];
        float a1 = arow[AW + k];
        float a2 = arow[2 * AW + k];
        float a3 = arow[3 * AW + k];
        float4 w0 = *(const float4*)&wcol[k * DIM];
        float4 w1 = *(const float4*)&wcol[k * DIM + 4];
        acc[0][0].x += a0 * w0.x; acc[0][0].y += a0 * w0.y; acc[0][0].z += a0 * w0.z; acc[0][0].w += a0 * w0.w;
        acc[0][1].x += a0 * w1.x; acc[0][1].y += a0 * w1.y; acc[0][1].z += a0 * w1.z; acc[0][1].w += a0 * w1.w;
        acc[1][0].x += a1 * w0.x; acc[1][0].y += a1 * w0.y; acc[1][0].z += a1 * w0.z; acc[1][0].w += a1 * w0.w;
        acc[1][1].x += a1 * w1.x; acc[1][1].y += a1 * w1.y; acc[1][1].z += a1 * w1.z; acc[1][1].w += a1 * w1.w;
        acc[2][0].x += a2 * w0.x; acc[2][0].y += a2 * w0.y; acc[2][0].z += a2 * w0.z; acc[2][0].w += a2 * w0.w;
        acc[2][1].x += a2 * w1.x; acc[2][1].y += a2 * w1.y; acc[2][1].z += a2 * w1.z; acc[2][1].w += a2 * w1.w;
        acc[3][0].x += a3 * w0.x; acc[3][0].y += a3 * w0.y; acc[3][0].z += a3 * w0.z; acc[3][0].w += a3 * w0.w;
        acc[3][1].x += a3 * w1.x; acc[3][1].y += a3 * w1.y; acc[3][1].z += a3 * w1.z; acc[3][1].w += a3 * w1.w;
    }
    #pragma unroll
    for (int r = 0; r < 4; r++) {
        int row = row0 + 4 * ty + r;
        if (row >= N_NODES) break;
        float di = dinv[row];
        uint4 pk;
        pk.x = (unsigned)f2bf(di * acc[r][0].x) | ((unsigned)f2bf(di * acc[r][0].y) << 16);
        pk.y = (unsigned)f2bf(di * acc[r][0].z) | ((unsigned)f2bf(di * acc[r][0].w) << 16);
        pk.z = (unsigned)f2bf(di * acc[r][1].x) | ((unsigned)f2bf(di * acc[r][1].y) << 16);
        pk.w = (unsigned)f2bf(di * acc[r][1].z) | ((unsigned)f2bf(di * acc[r][1].w) << 16);
        *(uint4*)&v2b[(size_t)row * DIM + tx * 8] = pk;
    }
}

// ---------------- layer-2 agg: contiguous segments, dual-buffered csr chunks,
// register pool accumulation with boundary flush ----------------
__global__ __launch_bounds__(256) void k_agg2(
    const unsigned* __restrict__ v2u, const float* __restrict__ dinv,
    const int* __restrict__ rowstart, const int* __restrict__ csr_src,
    const int* __restrict__ batch,
    const float* __restrict__ b2, const float* __restrict__ g2,
    const float* __restrict__ be2, float* __restrict__ pooled) {
    int lane = threadIdx.x & 63;
    int wave = (blockIdx.x * blockDim.x + threadIdx.x) >> 6;
    int i0 = wave * SEG;
    if (i0 >= N_NODES) return;
    int i1 = i0 + SEG; if (i1 > N_NODES) i1 = N_NODES;
    int nseg = i1 - i0;

    float2 bb = make_float2(b2[2 * lane], b2[2 * lane + 1]);
    float2 gg = make_float2(g2[2 * lane], g2[2 * lane + 1]);
    float2 eb = make_float2(be2[2 * lane], be2[2 * lane + 1]);

    int rsv = 0;
    if (lane <= nseg) rsv = rowstart[i0 + lane];
    float dv = 0.f; int bv = 0;
    if (lane < nseg) { dv = dinv[i0 + lane]; bv = batch[i0 + lane]; }

    int base = __shfl(rsv, 0, 64);
    int segend = __shfl(rsv, nseg, 64);

    int p0 = base;
    int buf0 = (base + lane < segend) ? csr_src[base + lane] : 0;
    int buf1 = (base + 64 + lane < segend) ? csr_src[base + 64 + lane] : 0;

    float px = 0.f, py = 0.f;
    int cur_g = __shfl(bv, 0, 64);
    int rs = base;
    for (int i = i0; i < i1; i++) {
        int k = i - i0;
        int re = __shfl(rsv, k + 1, 64);
        float di = __shfl(dv, k, 64);
        int g = __shfl(bv, k, 64);
        unsigned u0 = v2u[(size_t)i * 64 + lane];  // self term
        float ax = __uint_as_float(u0 << 16);
        float ay = __uint_as_float(u0 & 0xFFFF0000u);
        int e = rs;
        while (e < re) {
            int off = e - p0;
            if (off >= 64) {
                p0 += 64;
                buf0 = buf1;
                buf1 = (p0 + 64 + lane < segend) ? csr_src[p0 + 64 + lane] : 0;
                off -= 64;
            }
            int n = re - e;
            int avail = 64 - off;
            if (n > avail) n = avail;
            int j = 0;
            for (; j + 8 <= n; j += 8) {
                #pragma unroll
                for (int u = 0; u < 8; u++) {
                    int s = __shfl(buf0, off + j + u, 64);
                    unsigned uv = v2u[(size_t)s * 64 + lane];
                    ax += __uint_as_float(uv << 16);
                    ay += __uint_as_float(uv & 0xFFFF0000u);
                }
            }
            for (; j < n; j++) {
                int s = __shfl(buf0, off + j, 64);
                unsigned uv = v2u[(size_t)s * 64 + lane];
                ax += __uint_as_float(uv << 16);
                ay += __uint_as_float(uv & 0xFFFF0000u);
            }
            e += n;
        }
        rs = re;
        float a0 = di * ax + bb.x, a1 = di * ay + bb.y;
        float s = a0 + a1;
        #pragma unroll
        for (int m = 1; m < 64; m <<= 1) s += __shfl_xor(s, m, 64);
        float mu = s * (1.f / 128.f);
        float d0 = a0 - mu, d1 = a1 - mu;
        float q = d0 * d0 + d1 * d1;
        #pragma unroll
        for (int m = 1; m < 64; m <<= 1) q += __shfl_xor(q, m, 64);
        float r = rsqrtf(q * (1.f / 128.f) + LN_EPS);
        float o0 = fmaxf(d0 * r * gg.x + eb.x, 0.f);
        float o1 = fmaxf(d1 * r * gg.y + eb.y, 0.f);
        if (g != cur_g) {
            atomicAdd(&pooled[cur_g * DIM + 2 * lane], px);
            atomicAdd(&pooled[cur_g * DIM + 2 * lane + 1], py);
            px = 0.f; py = 0.f; cur_g = g;
        }
        px += o0; py += o1;
    }
    atomicAdd(&pooled[cur_g * DIM + 2 * lane], px);
    atomicAdd(&pooled[cur_g * DIM + 2 * lane + 1], py);
}

// ---------------- out[g] = pooled[g].fcW / max(cnt,1) + fcb ----------------
__global__ void k_out(const float* __restrict__ pooled, const int* __restrict__ starts,
                      const float* __restrict__ fcW, const float* __restrict__ fcb,
                      float* __restrict__ out) {
    int lane = threadIdx.x & 63;
    int g = (blockIdx.x * blockDim.x + threadIdx.x) >> 6;
    if (g >= N_GRAPHS) return;
    float2 p = ((const float2*)pooled)[g * 64 + lane];
    float2 w = ((const float2*)fcW)[lane];
    float s = p.x * w.x + p.y * w.y;
    #pragma unroll
    for (int m = 1; m < 64; m <<= 1) s += __shfl_xor(s, m, 64);
    if (lane == 0) {
        float c = (float)(starts[g + 1] - starts[g]);
        if (c < 1.f) c = 1.f;
        out[g] = s / c + fcb[0];
    }
}

extern "C" void kernel_launch(void* const* d_in, const int* in_sizes, int n_in,
                              void* d_out, int out_size, void* d_ws, size_t ws_size,
                              hipStream_t stream) {
    (void)in_sizes; (void)n_in; (void)out_size; (void)ws_size;
    const int* x    = (const int*)d_in[0];
    const int* src  = (const int*)d_in[1];
    const int* dst  = src + N_EDGES;
    const int* batch = (const int*)d_in[2];
    const float* emb = (const float*)d_in[3];
    const float* W1  = (const float*)d_in[4];
    const float* b1  = (const float*)d_in[5];
    const float* g1  = (const float*)d_in[6];
    const float* be1 = (const float*)d_in[7];
    const float* W2  = (const float*)d_in[8];
    const float* b2  = (const float*)d_in[9];
    const float* g2  = (const float*)d_in[10];
    const float* be2 = (const float*)d_in[11];
    const float* fcW = (const float*)d_in[12];
    const float* fcb = (const float*)d_in[13];
    float* out = (float*)d_out;

    char* wsp = (char*)d_ws;
    size_t off = 0;
    auto alloc = [&](size_t bytes) -> void* {
        void* p = wsp + off;
        off += (bytes + 15) & ~(size_t)15;
        return p;
    };
    // ---- zeroed region ----
    int*   deg      = (int*)alloc(N_NODES * 4);
    int*   cursor   = (int*)alloc(N_NODES * 4);
    float* pooled   = (float*)alloc(N_GRAPHS * DIM * 4);
    size_t zero_bytes = off;
    // ---- scratch ----
    int*      rowstart = (int*)alloc((N_NODES + 1) * 4);
    float*    dinv     = (float*)alloc(N_NODES * 4);
    unsigned* pw       = (unsigned*)alloc(N_NODES * 4);
    int*      csr_src  = (int*)alloc(N_EDGES * 4);
    float*    EW1      = (float*)alloc(VOCAB * DIM * 4);
    int*      starts   = (int*)alloc((N_GRAPHS + 1) * 4);
    int*      bsum     = (int*)alloc(NB * 4);
    int*      bofs     = (int*)alloc(NB * 4);
    float*    h1       = (float*)alloc((size_t)N_NODES * DIM * 4);
    unsigned short* v2b = (unsigned short*)alloc((size_t)N_NODES * DIM * 2);

    hipMemsetAsync(d_ws, 0, zero_bytes, stream);

    k_deg<<<(N_EDGES + 255) / 256, 256, 0, stream>>>(dst, deg);
    k_starts<<<3, 256, 0, stream>>>(batch, starts);
    kb_sum<<<NB, 256, 0, stream>>>(deg, bsum);
    kb_scan<<<1, 256, 0, stream>>>(bsum, bofs, rowstart);
    kb_emit<<<NB, 256, 0, stream>>>(deg, bofs, x, rowstart, dinv, pw);
    k_scatter<<<(N_EDGES + 255) / 256, 256, 0, stream>>>(src, dst, rowstart, cursor, csr_src);
    k_ew1<<<(VOCAB * DIM + 255) / 256, 256, 0, stream>>>(emb, W1, EW1);
    // 768 blocks x 512 thr = 3 blocks/CU (153.6 KB LDS), 24 waves/CU
    k_agg1<<<768, 512, 0, stream>>>(EW1, pw, dinv, rowstart, csr_src, b1, g1, be1,
                                    (float2*)h1);
    k_mm2<<<(N_NODES + 127) / 128, 512, 0, stream>>>(h1, W2, dinv, v2b);
    {
        int nwaves = (N_NODES + SEG - 1) / SEG;          // 6250
        int nblocks = (nwaves + 3) / 4;                  // 4 waves/block
        k_agg2<<<nblocks, 256, 0, stream>>>((const unsigned*)v2b, dinv, rowstart, csr_src,
                                            batch, b2, g2, be2, pooled);
    }
    k_out<<<(N_GRAPHS * 64 + 255) / 256, 256, 0, stream>>>(pooled, starts, fcW, fcb, out);
}

// Round 8
// 288.691 us; speedup vs baseline: 1.8338x; 1.0227x over previous
//
#include <hip/hip_runtime.h>
#include <hip/hip_fp16.h>
#include <math.h>

#define N_NODES 50000
#define N_EDGES 800000
#define VOCAB 100
#define DIM 128
#define N_GRAPHS 512
#define LN_EPS 1e-5f
#define NB 196   // ceil(N_NODES/256)
#define SEG 8    // nodes per wave in k_agg2
#define NWIN 8                                   // dst windows (== XCDs)
#define WSZ ((N_NODES + NWIN - 1) / NWIN)        // 6250 nodes per window

__device__ __forceinline__ unsigned short f2bf(float f) {
    unsigned u = __float_as_uint(f);
    return (unsigned short)((u + 0x7FFF + ((u >> 16) & 1)) >> 16);  // RNE
}

// ---------------- degree (XCD-windowed: atomics stay in one XCD's L2) ----------------
__global__ __launch_bounds__(256) void k_deg(const int* __restrict__ dst,
                                             int* __restrict__ deg) {
    int w = blockIdx.x & (NWIN - 1);      // window == XCD (round-robin heuristic)
    int bg = blockIdx.x >> 3;
    int lo = w * WSZ, hi = lo + WSZ; if (hi > N_NODES) hi = N_NODES;
    int stride = (gridDim.x >> 3) * 256;
    for (int e = bg * 256 + threadIdx.x; e < N_EDGES; e += stride) {
        int d = dst[e];
        if (d >= lo && d < hi) atomicAdd(&deg[d], 1);
    }
}

// ---------------- graph starts via binary search (batch is sorted) ----------------
__global__ void k_starts(const int* __restrict__ batch, int* __restrict__ starts) {
    int g = blockIdx.x * blockDim.x + threadIdx.x;
    if (g > N_GRAPHS) return;
    int lo = 0, hi = N_NODES;
    while (lo < hi) { int mid = (lo + hi) >> 1; if (batch[mid] < g) lo = mid + 1; else hi = mid; }
    starts[g] = lo;
}

// ---------------- 3-phase multi-block scan ----------------
__global__ __launch_bounds__(256) void kb_sum(const int* __restrict__ deg,
                                              int* __restrict__ bsum) {
    int i = blockIdx.x * 256 + threadIdx.x;
    int v = (i < N_NODES) ? deg[i] : 0;
    #pragma unroll
    for (int m = 1; m < 64; m <<= 1) v += __shfl_xor(v, m, 64);
    __shared__ int ws[4];
    int lane = threadIdx.x & 63, w = threadIdx.x >> 6;
    if (lane == 0) ws[w] = v;
    __syncthreads();
    if (threadIdx.x == 0) bsum[blockIdx.x] = ws[0] + ws[1] + ws[2] + ws[3];
}

__global__ __launch_bounds__(256) void kb_scan(const int* __restrict__ bsum,
                                               int* __restrict__ bofs,
                                               int* __restrict__ rowstart) {
    int t = threadIdx.x, lane = t & 63, w = t >> 6;
    int v = (t < NB) ? bsum[t] : 0;
    int incl = v;
    #pragma unroll
    for (int off = 1; off < 64; off <<= 1) {
        int u = __shfl_up(incl, off, 64);
        if (lane >= off) incl += u;
    }
    __shared__ int ws[4];
    if (lane == 63) ws[w] = incl;
    __syncthreads();
    int add = 0;
    for (int k = 0; k < w; k++) add += ws[k];
    incl += add;
    if (t < NB) bofs[t] = incl - v;
    if (t == 255) rowstart[N_NODES] = incl;
}

// emits rowstart, dinv (fp32), and pw[i] = (fp16(dinv_i)<<16) | x_i
__global__ __launch_bounds__(256) void kb_emit(const int* __restrict__ deg,
                                               const int* __restrict__ bofs,
                                               const int* __restrict__ x,
                                               int* __restrict__ rowstart,
                                               float* __restrict__ dinv,
                                               unsigned* __restrict__ pw) {
    int b = blockIdx.x, t = threadIdx.x, i = b * 256 + t;
    int lane = t & 63, w = t >> 6;
    int v = (i < N_NODES) ? deg[i] : 0;
    int incl = v;
    #pragma unroll
    for (int off = 1; off < 64; off <<= 1) {
        int u = __shfl_up(incl, off, 64);
        if (lane >= off) incl += u;
    }
    __shared__ int ws[4];
    if (lane == 63) ws[w] = incl;
    __syncthreads();
    int add = bofs[b];
    for (int k = 0; k < w; k++) add += ws[k];
    if (i < N_NODES) {
        rowstart[i] = add + incl - v;
        float dv = rsqrtf((float)v + 1.0f);
        dinv[i] = dv;
        unsigned hb = (unsigned)__half_as_ushort(__float2half_rn(dv));
        pw[i] = (hb << 16) | (unsigned)x[i];
    }
}

// ---------------- CSR scatter (XCD-windowed: writes combine in one XCD's L2) ----------------
__global__ __launch_bounds__(256) void k_scatter(const int* __restrict__ src,
                                                 const int* __restrict__ dst,
                                                 const int* __restrict__ rowstart,
                                                 int* __restrict__ cursor,
                                                 int* __restrict__ csr_src) {
    int w = blockIdx.x & (NWIN - 1);
    int bg = blockIdx.x >> 3;
    int lo = w * WSZ, hi = lo + WSZ; if (hi > N_NODES) hi = N_NODES;
    int stride = (gridDim.x >> 3) * 256;
    for (int e = bg * 256 + threadIdx.x; e < N_EDGES; e += stride) {
        int d = dst[e];
        if (d >= lo && d < hi) {
            int pos = rowstart[d] + atomicAdd(&cursor[d], 1);
            csr_src[pos] = src[e];
        }
    }
}

// ---------------- EW1 = emb @ W1 (tiny: 100x128) ----------------
__global__ void k_ew1(const float* __restrict__ emb, const float* __restrict__ W1,
                      float* __restrict__ EW1) {
    int idx = blockIdx.x * blockDim.x + threadIdx.x;
    if (idx >= VOCAB * DIM) return;
    int r = idx >> 7, c = idx & 127;
    float acc = 0.f;
    for (int k = 0; k < DIM; k++) acc += emb[r * DIM + k] * W1[k * DIM + c];
    EW1[idx] = acc;
}

// ---------------- layer-1 agg + LN + ReLU ----------------
__global__ __launch_bounds__(512) void k_agg1(
    const float* __restrict__ EW1, const unsigned* __restrict__ pw,
    const float* __restrict__ dinv,
    const int* __restrict__ rowstart, const int* __restrict__ csr_src,
    const float* __restrict__ b1, const float* __restrict__ g1,
    const float* __restrict__ be1, float2* __restrict__ h1) {
    __shared__ float2 ew[VOCAB * 64];  // 51200 B
    for (int idx = threadIdx.x; idx < VOCAB * 64; idx += blockDim.x)
        ew[idx] = ((const float2*)EW1)[idx];
    __syncthreads();
    int lane = threadIdx.x & 63;
    int wave = (blockIdx.x * blockDim.x + threadIdx.x) >> 6;
    int nw = (gridDim.x * blockDim.x) >> 6;
    float2 bb = make_float2(b1[2 * lane], b1[2 * lane + 1]);
    float2 gg = make_float2(g1[2 * lane], g1[2 * lane + 1]);
    float2 eb = make_float2(be1[2 * lane], be1[2 * lane + 1]);
    for (int i = wave; i < N_NODES; i += nw) {
        float di = dinv[i];
        int xi = (int)(pw[i] & 0xFFFFu);
        float2 e0 = ew[xi * 64 + lane];
        float ax = di * e0.x, ay = di * e0.y;  // self-loop: dinv_i * EW1[x_i] (fp32)
        int p = rowstart[i], pe = rowstart[i + 1];
        while (p < pe) {
            int n = pe - p; if (n > 64) n = 64;
            unsigned myw = 0;
            if (lane < n) myw = pw[csr_src[p + lane]];
            int j = 0;
            for (; j + 8 <= n; j += 8) {
                #pragma unroll
                for (int u = 0; u < 8; u++) {
                    unsigned w = (unsigned)__shfl((int)myw, j + u, 64);
                    int xv = (int)(w & 0xFFFFu);
                    float ds = __half2float(__ushort_as_half((unsigned short)(w >> 16)));
                    float2 es = ew[xv * 64 + lane];
                    ax += ds * es.x; ay += ds * es.y;
                }
            }
            for (; j < n; j++) {
                unsigned w = (unsigned)__shfl((int)myw, j, 64);
                int xv = (int)(w & 0xFFFFu);
                float ds = __half2float(__ushort_as_half((unsigned short)(w >> 16)));
                float2 es = ew[xv * 64 + lane];
                ax += ds * es.x; ay += ds * es.y;
            }
            p += n;
        }
        float a0 = di * ax + bb.x, a1 = di * ay + bb.y;
        float s = a0 + a1;
        #pragma unroll
        for (int m = 1; m < 64; m <<= 1) s += __shfl_xor(s, m, 64);
        float mu = s * (1.f / 128.f);
        float d0 = a0 - mu, d1 = a1 - mu;
        float q = d0 * d0 + d1 * d1;
        #pragma unroll
        for (int m = 1; m < 64; m <<= 1) q += __shfl_xor(q, m, 64);
        float r = rsqrtf(q * (1.f / 128.f) + LN_EPS);
        float o0 = fmaxf(d0 * r * gg.x + eb.x, 0.f);
        float o1 = fmaxf(d1 * r * gg.y + eb.y, 0.f);
        h1[i * 64 + lane] = make_float2(o0, o1);
    }
}

// ---------------- v2 = bf16( dinv * (h1 @ W2) ) ----------------
#define AW 132
__global__ __launch_bounds__(512) void k_mm2(
    const float* __restrict__ h1, const float* __restrict__ W2,
    const float* __restrict__ dinv, unsigned short* __restrict__ v2b) {
    __shared__ float w[DIM * DIM];    // 65536 B
    __shared__ float at[128 * AW];    // 67584 B
    int t = threadIdx.x;
    for (int idx = t * 4; idx < DIM * DIM; idx += 2048)
        *(float4*)&w[idx] = *(const float4*)&W2[idx];
    int row0 = blockIdx.x * 128;
    for (int idx = t * 4; idx < 128 * DIM; idx += 2048) {
        int r = idx >> 7, c = idx & 127;
        int row = row0 + r;
        float4 val = make_float4(0.f, 0.f, 0.f, 0.f);
        if (row < N_NODES) val = *(const float4*)&h1[(size_t)row * DIM + c];
        *(float4*)&at[r * AW + c] = val;
    }
    __syncthreads();
    int tx = t & 15;
    int ty = t >> 4;
    float4 acc[4][2];
    #pragma unroll
    for (int r = 0; r < 4; r++) {
        acc[r][0] = make_float4(0.f, 0.f, 0.f, 0.f);
        acc[r][1] = make_float4(0.f, 0.f, 0.f, 0.f);
    }
    const float* arow = &at[(4 * ty) * AW];
    const float* wcol = &w[tx * 8];
    #pragma unroll 4
    for (int k = 0; k < DIM; k++) {
        float a0 = arow[k];
        float a1 = arow[AW + k];
        float a2 = arow[2 * AW + k];
        float a3 = arow[3 * AW + k];
        float4 w0 = *(const float4*)&wcol[k * DIM];
        float4 w1 = *(const float4*)&wcol[k * DIM + 4];
        acc[0][0].x += a0 * w0.x; acc[0][0].y += a0 * w0.y; acc[0][0].z += a0 * w0.z; acc[0][0].w += a0 * w0.w;
        acc[0][1].x += a0 * w1.x; acc[0][1].y += a0 * w1.y; acc[0][1].z += a0 * w1.z; acc[0][1].w += a0 * w1.w;
        acc[1][0].x += a1 * w0.x; acc[1][0].y += a1 * w0.y; acc[1][0].z += a1 * w0.z; acc[1][0].w += a1 * w0.w;
        acc[1][1].x += a1 * w1.x; acc[1][1].y += a1 * w1.y; acc[1][1].z += a1 * w1.z; acc[1][1].w += a1 * w1.w;
        acc[2][0].x += a2 * w0.x; acc[2][0].y += a2 * w0.y; acc[2][0].z += a2 * w0.z; acc[2][0].w += a2 * w0.w;
        acc[2][1].x += a2 * w1.x; acc[2][1].y += a2 * w1.y; acc[2][1].z += a2 * w1.z; acc[2][1].w += a2 * w1.w;
        acc[3][0].x += a3 * w0.x; acc[3][0].y += a3 * w0.y; acc[3][0].z += a3 * w0.z; acc[3][0].w += a3 * w0.w;
        acc[3][1].x += a3 * w1.x; acc[3][1].y += a3 * w1.y; acc[3][1].z += a3 * w1.z; acc[3][1].w += a3 * w1.w;
    }
    #pragma unroll
    for (int r = 0; r < 4; r++) {
        int row = row0 + 4 * ty + r;
        if (row >= N_NODES) break;
        float di = dinv[row];
        uint4 pk;
        pk.x = (unsigned)f2bf(di * acc[r][0].x) | ((unsigned)f2bf(di * acc[r][0].y) << 16);
        pk.y = (unsigned)f2bf(di * acc[r][0].z) | ((unsigned)f2bf(di * acc[r][0].w) << 16);
        pk.z = (unsigned)f2bf(di * acc[r][1].x) | ((unsigned)f2bf(di * acc[r][1].y) << 16);
        pk.w = (unsigned)f2bf(di * acc[r][1].z) | ((unsigned)f2bf(di * acc[r][1].w) << 16);
        *(uint4*)&v2b[(size_t)row * DIM + tx * 8] = pk;
    }
}

// ---------------- layer-2 agg: contiguous segments, dual-buffered csr chunks,
// register pool accumulation with boundary flush ----------------
__global__ __launch_bounds__(256) void k_agg2(
    const unsigned* __restrict__ v2u, const float* __restrict__ dinv,
    const int* __restrict__ rowstart, const int* __restrict__ csr_src,
    const int* __restrict__ batch,
    const float* __restrict__ b2, const float* __restrict__ g2,
    const float* __restrict__ be2, float* __restrict__ pooled) {
    int lane = threadIdx.x & 63;
    int wave = (blockIdx.x * blockDim.x + threadIdx.x) >> 6;
    int i0 = wave * SEG;
    if (i0 >= N_NODES) return;
    int i1 = i0 + SEG; if (i1 > N_NODES) i1 = N_NODES;
    int nseg = i1 - i0;

    float2 bb = make_float2(b2[2 * lane], b2[2 * lane + 1]);
    float2 gg = make_float2(g2[2 * lane], g2[2 * lane + 1]);
    float2 eb = make_float2(be2[2 * lane], be2[2 * lane + 1]);

    int rsv = 0;
    if (lane <= nseg) rsv = rowstart[i0 + lane];
    float dv = 0.f; int bv = 0;
    if (lane < nseg) { dv = dinv[i0 + lane]; bv = batch[i0 + lane]; }

    int base = __shfl(rsv, 0, 64);
    int segend = __shfl(rsv, nseg, 64);

    int p0 = base;
    int buf0 = (base + lane < segend) ? csr_src[base + lane] : 0;
    int buf1 = (base + 64 + lane < segend) ? csr_src[base + 64 + lane] : 0;

    float px = 0.f, py = 0.f;
    int cur_g = __shfl(bv, 0, 64);
    int rs = base;
    for (int i = i0; i < i1; i++) {
        int k = i - i0;
        int re = __shfl(rsv, k + 1, 64);
        float di = __shfl(dv, k, 64);
        int g = __shfl(bv, k, 64);
        unsigned u0 = v2u[(size_t)i * 64 + lane];  // self term
        float ax = __uint_as_float(u0 << 16);
        float ay = __uint_as_float(u0 & 0xFFFF0000u);
        int e = rs;
        while (e < re) {
            int off = e - p0;
            if (off >= 64) {
                p0 += 64;
                buf0 = buf1;
                buf1 = (p0 + 64 + lane < segend) ? csr_src[p0 + 64 + lane] : 0;
                off -= 64;
            }
            int n = re - e;
            int avail = 64 - off;
            if (n > avail) n = avail;
            int j = 0;
            for (; j + 8 <= n; j += 8) {
                #pragma unroll
                for (int u = 0; u < 8; u++) {
                    int s = __shfl(buf0, off + j + u, 64);
                    unsigned uv = v2u[(size_t)s * 64 + lane];
                    ax += __uint_as_float(uv << 16);
                    ay += __uint_as_float(uv & 0xFFFF0000u);
                }
            }
            for (; j < n; j++) {
                int s = __shfl(buf0, off + j, 64);
                unsigned uv = v2u[(size_t)s * 64 + lane];
                ax += __uint_as_float(uv << 16);
                ay += __uint_as_float(uv & 0xFFFF0000u);
            }
            e += n;
        }
        rs = re;
        float a0 = di * ax + bb.x, a1 = di * ay + bb.y;
        float s = a0 + a1;
        #pragma unroll
        for (int m = 1; m < 64; m <<= 1) s += __shfl_xor(s, m, 64);
        float mu = s * (1.f / 128.f);
        float d0 = a0 - mu, d1 = a1 - mu;
        float q = d0 * d0 + d1 * d1;
        #pragma unroll
        for (int m = 1; m < 64; m <<= 1) q += __shfl_xor(q, m, 64);
        float r = rsqrtf(q * (1.f / 128.f) + LN_EPS);
        float o0 = fmaxf(d0 * r * gg.x + eb.x, 0.f);
        float o1 = fmaxf(d1 * r * gg.y + eb.y, 0.f);
        if (g != cur_g) {
            atomicAdd(&pooled[cur_g * DIM + 2 * lane], px);
            atomicAdd(&pooled[cur_g * DIM + 2 * lane + 1], py);
            px = 0.f; py = 0.f; cur_g = g;
        }
        px += o0; py += o1;
    }
    atomicAdd(&pooled[cur_g * DIM + 2 * lane], px);
    atomicAdd(&pooled[cur_g * DIM + 2 * lane + 1], py);
}

// ---------------- out[g] = pooled[g].fcW / max(cnt,1) + fcb ----------------
__global__ void k_out(const float* __restrict__ pooled, const int* __restrict__ starts,
                      const float* __restrict__ fcW, const float* __restrict__ fcb,
                      float* __restrict__ out) {
    int lane = threadIdx.x & 63;
    int g = (blockIdx.x * blockDim.x + threadIdx.x) >> 6;
    if (g >= N_GRAPHS) return;
    float2 p = ((const float2*)pooled)[g * 64 + lane];
    float2 w = ((const float2*)fcW)[lane];
    float s = p.x * w.x + p.y * w.y;
    #pragma unroll
    for (int m = 1; m < 64; m <<= 1) s += __shfl_xor(s, m, 64);
    if (lane == 0) {
        float c = (float)(starts[g + 1] - starts[g]);
        if (c < 1.f) c = 1.f;
        out[g] = s / c + fcb[0];
    }
}

extern "C" void kernel_launch(void* const* d_in, const int* in_sizes, int n_in,
                              void* d_out, int out_size, void* d_ws, size_t ws_size,
                              hipStream_t stream) {
    (void)in_sizes; (void)n_in; (void)out_size; (void)ws_size;
    const int* x    = (const int*)d_in[0];
    const int* src  = (const int*)d_in[1];
    const int* dst  = src + N_EDGES;
    const int* batch = (const int*)d_in[2];
    const float* emb = (const float*)d_in[3];
    const float* W1  = (const float*)d_in[4];
    const float* b1  = (const float*)d_in[5];
    const float* g1  = (const float*)d_in[6];
    const float* be1 = (const float*)d_in[7];
    const float* W2  = (const float*)d_in[8];
    const float* b2  = (const float*)d_in[9];
    const float* g2  = (const float*)d_in[10];
    const float* be2 = (const float*)d_in[11];
    const float* fcW = (const float*)d_in[12];
    const float* fcb = (const float*)d_in[13];
    float* out = (float*)d_out;

    char* wsp = (char*)d_ws;
    size_t off = 0;
    auto alloc = [&](size_t bytes) -> void* {
        void* p = wsp + off;
        off += (bytes + 15) & ~(size_t)15;
        return p;
    };
    // ---- zeroed region ----
    int*   deg      = (int*)alloc(N_NODES * 4);
    int*   cursor   = (int*)alloc(N_NODES * 4);
    float* pooled   = (float*)alloc(N_GRAPHS * DIM * 4);
    size_t zero_bytes = off;
    // ---- scratch ----
    int*      rowstart = (int*)alloc((N_NODES + 1) * 4);
    float*    dinv     = (float*)alloc(N_NODES * 4);
    unsigned* pw       = (unsigned*)alloc(N_NODES * 4);
    int*      csr_src  = (int*)alloc(N_EDGES * 4);
    float*    EW1      = (float*)alloc(VOCAB * DIM * 4);
    int*      starts   = (int*)alloc((N_GRAPHS + 1) * 4);
    int*      bsum     = (int*)alloc(NB * 4);
    int*      bofs     = (int*)alloc(NB * 4);
    float*    h1       = (float*)alloc((size_t)N_NODES * DIM * 4);
    unsigned short* v2b = (unsigned short*)alloc((size_t)N_NODES * DIM * 2);

    hipMemsetAsync(d_ws, 0, zero_bytes, stream);

    // windowed kernels: 2048 blocks = 256 per window-group, blockIdx&7 == window/XCD
    k_deg<<<2048, 256, 0, stream>>>(dst, deg);
    k_starts<<<3, 256, 0, stream>>>(batch, starts);
    kb_sum<<<NB, 256, 0, stream>>>(deg, bsum);
    kb_scan<<<1, 256, 0, stream>>>(bsum, bofs, rowstart);
    kb_emit<<<NB, 256, 0, stream>>>(deg, bofs, x, rowstart, dinv, pw);
    k_scatter<<<2048, 256, 0, stream>>>(src, dst, rowstart, cursor, csr_src);
    k_ew1<<<(VOCAB * DIM + 255) / 256, 256, 0, stream>>>(emb, W1, EW1);
    // 768 blocks x 512 thr = 3 blocks/CU (153.6 KB LDS), 24 waves/CU
    k_agg1<<<768, 512, 0, stream>>>(EW1, pw, dinv, rowstart, csr_src, b1, g1, be1,
                                    (float2*)h1);
    k_mm2<<<(N_NODES + 127) / 128, 512, 0, stream>>>(h1, W2, dinv, v2b);
    {
        int nwaves = (N_NODES + SEG - 1) / SEG;          // 6250
        int nblocks = (nwaves + 3) / 4;                  // 4 waves/block
        k_agg2<<<nblocks, 256, 0, stream>>>((const unsigned*)v2b, dinv, rowstart, csr_src,
                                            batch, b2, g2, be2, pooled);
    }
    k_out<<<(N_GRAPHS * 64 + 255) / 256, 256, 0, stream>>>(pooled, starts, fcW, fcb, out);
}

// Round 9
// 272.389 us; speedup vs baseline: 1.9436x; 1.0599x over previous
//
#include <hip/hip_runtime.h>
#include <hip/hip_fp16.h>
#include <math.h>

#define N_NODES 50000
#define N_EDGES 800000
#define VOCAB 100
#define DIM 128
#define N_GRAPHS 512
#define LN_EPS 1e-5f
#define NB 196   // ceil(N_NODES/256)
#define SEG 8    // nodes per wave in k_agg2
#define NWIN 8                                   // dst windows (== XCDs)
#define WSZ ((N_NODES + NWIN - 1) / NWIN)        // 6250 nodes per window

using bf16x8  = __attribute__((ext_vector_type(8))) __bf16;
using floatx4 = __attribute__((ext_vector_type(4))) float;

__device__ __forceinline__ unsigned short f2bf(float f) {
    unsigned u = __float_as_uint(f);
    return (unsigned short)((u + 0x7FFF + ((u >> 16) & 1)) >> 16);  // RNE
}

// ---------------- degree (XCD-windowed: atomics stay in one XCD's L2) ----------------
__global__ __launch_bounds__(256) void k_deg(const int* __restrict__ dst,
                                             int* __restrict__ deg) {
    int w = blockIdx.x & (NWIN - 1);
    int bg = blockIdx.x >> 3;
    int lo = w * WSZ, hi = lo + WSZ; if (hi > N_NODES) hi = N_NODES;
    int stride = (gridDim.x >> 3) * 256;
    for (int e = bg * 256 + threadIdx.x; e < N_EDGES; e += stride) {
        int d = dst[e];
        if (d >= lo && d < hi) atomicAdd(&deg[d], 1);
    }
}

// ---------------- graph starts via binary search (batch is sorted) ----------------
__global__ void k_starts(const int* __restrict__ batch, int* __restrict__ starts) {
    int g = blockIdx.x * blockDim.x + threadIdx.x;
    if (g > N_GRAPHS) return;
    int lo = 0, hi = N_NODES;
    while (lo < hi) { int mid = (lo + hi) >> 1; if (batch[mid] < g) lo = mid + 1; else hi = mid; }
    starts[g] = lo;
}

// ---------------- 3-phase multi-block scan ----------------
__global__ __launch_bounds__(256) void kb_sum(const int* __restrict__ deg,
                                              int* __restrict__ bsum) {
    int i = blockIdx.x * 256 + threadIdx.x;
    int v = (i < N_NODES) ? deg[i] : 0;
    #pragma unroll
    for (int m = 1; m < 64; m <<= 1) v += __shfl_xor(v, m, 64);
    __shared__ int ws[4];
    int lane = threadIdx.x & 63, w = threadIdx.x >> 6;
    if (lane == 0) ws[w] = v;
    __syncthreads();
    if (threadIdx.x == 0) bsum[blockIdx.x] = ws[0] + ws[1] + ws[2] + ws[3];
}

__global__ __launch_bounds__(256) void kb_scan(const int* __restrict__ bsum,
                                               int* __restrict__ bofs,
                                               int* __restrict__ rowstart) {
    int t = threadIdx.x, lane = t & 63, w = t >> 6;
    int v = (t < NB) ? bsum[t] : 0;
    int incl = v;
    #pragma unroll
    for (int off = 1; off < 64; off <<= 1) {
        int u = __shfl_up(incl, off, 64);
        if (lane >= off) incl += u;
    }
    __shared__ int ws[4];
    if (lane == 63) ws[w] = incl;
    __syncthreads();
    int add = 0;
    for (int k = 0; k < w; k++) add += ws[k];
    incl += add;
    if (t < NB) bofs[t] = incl - v;
    if (t == 255) rowstart[N_NODES] = incl;
}

// emits rowstart, dinv (fp32), and pw[i] = (fp16(dinv_i)<<16) | x_i
__global__ __launch_bounds__(256) void kb_emit(const int* __restrict__ deg,
                                               const int* __restrict__ bofs,
                                               const int* __restrict__ x,
                                               int* __restrict__ rowstart,
                                               float* __restrict__ dinv,
                                               unsigned* __restrict__ pw) {
    int b = blockIdx.x, t = threadIdx.x, i = b * 256 + t;
    int lane = t & 63, w = t >> 6;
    int v = (i < N_NODES) ? deg[i] : 0;
    int incl = v;
    #pragma unroll
    for (int off = 1; off < 64; off <<= 1) {
        int u = __shfl_up(incl, off, 64);
        if (lane >= off) incl += u;
    }
    __shared__ int ws[4];
    if (lane == 63) ws[w] = incl;
    __syncthreads();
    int add = bofs[b];
    for (int k = 0; k < w; k++) add += ws[k];
    if (i < N_NODES) {
        rowstart[i] = add + incl - v;
        float dv = rsqrtf((float)v + 1.0f);
        dinv[i] = dv;
        unsigned hb = (unsigned)__half_as_ushort(__float2half_rn(dv));
        pw[i] = (hb << 16) | (unsigned)x[i];
    }
}

// ---------------- CSR scatter (XCD-windowed) ----------------
__global__ __launch_bounds__(256) void k_scatter(const int* __restrict__ src,
                                                 const int* __restrict__ dst,
                                                 const int* __restrict__ rowstart,
                                                 int* __restrict__ cursor,
                                                 int* __restrict__ csr_src) {
    int w = blockIdx.x & (NWIN - 1);
    int bg = blockIdx.x >> 3;
    int lo = w * WSZ, hi = lo + WSZ; if (hi > N_NODES) hi = N_NODES;
    int stride = (gridDim.x >> 3) * 256;
    for (int e = bg * 256 + threadIdx.x; e < N_EDGES; e += stride) {
        int d = dst[e];
        if (d >= lo && d < hi) {
            int pos = rowstart[d] + atomicAdd(&cursor[d], 1);
            csr_src[pos] = src[e];
        }
    }
}

// ---------------- EW1 = emb @ W1 (tiny: 100x128) ----------------
__global__ void k_ew1(const float* __restrict__ emb, const float* __restrict__ W1,
                      float* __restrict__ EW1) {
    int idx = blockIdx.x * blockDim.x + threadIdx.x;
    if (idx >= VOCAB * DIM) return;
    int r = idx >> 7, c = idx & 127;
    float acc = 0.f;
    for (int k = 0; k < DIM; k++) acc += emb[r * DIM + k] * W1[k * DIM + c];
    EW1[idx] = acc;
}

// ---------------- layer-1 agg + LN + ReLU (bf16 h1 output) ----------------
__global__ __launch_bounds__(512) void k_agg1(
    const float* __restrict__ EW1, const unsigned* __restrict__ pw,
    const float* __restrict__ dinv,
    const int* __restrict__ rowstart, const int* __restrict__ csr_src,
    const float* __restrict__ b1, const float* __restrict__ g1,
    const float* __restrict__ be1, unsigned* __restrict__ h1b) {
    __shared__ float2 ew[VOCAB * 64];  // 51200 B
    for (int idx = threadIdx.x; idx < VOCAB * 64; idx += blockDim.x)
        ew[idx] = ((const float2*)EW1)[idx];
    __syncthreads();
    int lane = threadIdx.x & 63;
    int wave = (blockIdx.x * blockDim.x + threadIdx.x) >> 6;
    int nw = (gridDim.x * blockDim.x) >> 6;
    float2 bb = make_float2(b1[2 * lane], b1[2 * lane + 1]);
    float2 gg = make_float2(g1[2 * lane], g1[2 * lane + 1]);
    float2 eb = make_float2(be1[2 * lane], be1[2 * lane + 1]);
    for (int i = wave; i < N_NODES; i += nw) {
        float di = dinv[i];
        int xi = (int)(pw[i] & 0xFFFFu);
        float2 e0 = ew[xi * 64 + lane];
        float ax = di * e0.x, ay = di * e0.y;  // self-loop (fp32)
        int p = rowstart[i], pe = rowstart[i + 1];
        while (p < pe) {
            int n = pe - p; if (n > 64) n = 64;
            unsigned myw = 0;
            if (lane < n) myw = pw[csr_src[p + lane]];
            int j = 0;
            for (; j + 8 <= n; j += 8) {
                #pragma unroll
                for (int u = 0; u < 8; u++) {
                    unsigned w = (unsigned)__shfl((int)myw, j + u, 64);
                    int xv = (int)(w & 0xFFFFu);
                    float ds = __half2float(__ushort_as_half((unsigned short)(w >> 16)));
                    float2 es = ew[xv * 64 + lane];
                    ax += ds * es.x; ay += ds * es.y;
                }
            }
            for (; j < n; j++) {
                unsigned w = (unsigned)__shfl((int)myw, j, 64);
                int xv = (int)(w & 0xFFFFu);
                float ds = __half2float(__ushort_as_half((unsigned short)(w >> 16)));
                float2 es = ew[xv * 64 + lane];
                ax += ds * es.x; ay += ds * es.y;
            }
            p += n;
        }
        float a0 = di * ax + bb.x, a1 = di * ay + bb.y;
        float s = a0 + a1;
        #pragma unroll
        for (int m = 1; m < 64; m <<= 1) s += __shfl_xor(s, m, 64);
        float mu = s * (1.f / 128.f);
        float d0 = a0 - mu, d1 = a1 - mu;
        float q = d0 * d0 + d1 * d1;
        #pragma unroll
        for (int m = 1; m < 64; m <<= 1) q += __shfl_xor(q, m, 64);
        float r = rsqrtf(q * (1.f / 128.f) + LN_EPS);
        float o0 = fmaxf(d0 * r * gg.x + eb.x, 0.f);
        float o1 = fmaxf(d1 * r * gg.y + eb.y, 0.f);
        // bf16 store: identical rounding to what MFMA staging would apply
        h1b[(size_t)i * 64 + lane] = (unsigned)f2bf(o0) | ((unsigned)f2bf(o1) << 16);
    }
}

// ---------------- v2 = bf16( dinv * (h1 @ W2) ), MFMA 16x16x32 bf16 ----------------
// N_NODES = 16*3125 exactly: no guards. A-frags direct from global h1b
// (A[m=lane&15][k=quad*8+j]); B = W2^T bf16 in LDS [n][k], stride 144
// (288 B rows: 16B-aligned, 4-way bank alias = 1.58x only).
#define W2K 144
__global__ __launch_bounds__(512) void k_mm2(
    const unsigned short* __restrict__ h1b, const float* __restrict__ W2,
    const float* __restrict__ dinv, unsigned short* __restrict__ v2b) {
    __shared__ unsigned short w2t[DIM * W2K];  // 36864 B
    int t = threadIdx.x;
    for (int idx = t * 4; idx < DIM * DIM; idx += 2048) {
        int k = idx >> 7, n = idx & 127;
        float4 v = *(const float4*)&W2[idx];
        w2t[(n + 0) * W2K + k] = f2bf(v.x);
        w2t[(n + 1) * W2K + k] = f2bf(v.y);
        w2t[(n + 2) * W2K + k] = f2bf(v.z);
        w2t[(n + 3) * W2K + k] = f2bf(v.w);
    }
    __syncthreads();
    int lane = t & 63, wv = t >> 6;
    int m = lane & 15, quad = lane >> 4;
    const int NT = N_NODES / 16;  // 3125 row-tiles (exact)
    for (int tile = blockIdx.x * 8 + wv; tile < NT; tile += gridDim.x * 8) {
        const unsigned short* arow = &h1b[(size_t)(tile * 16 + m) * DIM + quad * 8];
        bf16x8 a0 = *(const bf16x8*)(arow);
        bf16x8 a1 = *(const bf16x8*)(arow + 32);
        bf16x8 a2 = *(const bf16x8*)(arow + 64);
        bf16x8 a3 = *(const bf16x8*)(arow + 96);
        int r0 = tile * 16 + quad * 4;
        float dv0 = dinv[r0], dv1 = dinv[r0 + 1], dv2 = dinv[r0 + 2], dv3 = dinv[r0 + 3];
        #pragma unroll
        for (int nt = 0; nt < 8; nt++) {
            const unsigned short* brow = &w2t[(nt * 16 + m) * W2K + quad * 8];
            bf16x8 b0 = *(const bf16x8*)(brow);
            bf16x8 b1 = *(const bf16x8*)(brow + 32);
            bf16x8 b2 = *(const bf16x8*)(brow + 64);
            bf16x8 b3 = *(const bf16x8*)(brow + 96);
            floatx4 c = {0.f, 0.f, 0.f, 0.f};
            c = __builtin_amdgcn_mfma_f32_16x16x32_bf16(a0, b0, c, 0, 0, 0);
            c = __builtin_amdgcn_mfma_f32_16x16x32_bf16(a1, b1, c, 0, 0, 0);
            c = __builtin_amdgcn_mfma_f32_16x16x32_bf16(a2, b2, c, 0, 0, 0);
            c = __builtin_amdgcn_mfma_f32_16x16x32_bf16(a3, b3, c, 0, 0, 0);
            int col = nt * 16 + m;  // C/D: col=lane&15, row=quad*4+reg (m89/m91)
            v2b[(size_t)(r0 + 0) * DIM + col] = f2bf(dv0 * c[0]);
            v2b[(size_t)(r0 + 1) * DIM + col] = f2bf(dv1 * c[1]);
            v2b[(size_t)(r0 + 2) * DIM + col] = f2bf(dv2 * c[2]);
            v2b[(size_t)(r0 + 3) * DIM + col] = f2bf(dv3 * c[3]);
        }
    }
}

// ---------------- layer-2 agg: contiguous segments, dual-buffered csr chunks,
// register pool accumulation with boundary flush ----------------
__global__ __launch_bounds__(256) void k_agg2(
    const unsigned* __restrict__ v2u, const float* __restrict__ dinv,
    const int* __restrict__ rowstart, const int* __restrict__ csr_src,
    const int* __restrict__ batch,
    const float* __restrict__ b2, const float* __restrict__ g2,
    const float* __restrict__ be2, float* __restrict__ pooled) {
    int lane = threadIdx.x & 63;
    int wave = (blockIdx.x * blockDim.x + threadIdx.x) >> 6;
    int i0 = wave * SEG;
    if (i0 >= N_NODES) return;
    int i1 = i0 + SEG; if (i1 > N_NODES) i1 = N_NODES;
    int nseg = i1 - i0;

    float2 bb = make_float2(b2[2 * lane], b2[2 * lane + 1]);
    float2 gg = make_float2(g2[2 * lane], g2[2 * lane + 1]);
    float2 eb = make_float2(be2[2 * lane], be2[2 * lane + 1]);

    int rsv = 0;
    if (lane <= nseg) rsv = rowstart[i0 + lane];
    float dv = 0.f; int bv = 0;
    if (lane < nseg) { dv = dinv[i0 + lane]; bv = batch[i0 + lane]; }

    int base = __shfl(rsv, 0, 64);
    int segend = __shfl(rsv, nseg, 64);

    int p0 = base;
    int buf0 = (base + lane < segend) ? csr_src[base + lane] : 0;
    int buf1 = (base + 64 + lane < segend) ? csr_src[base + 64 + lane] : 0;

    float px = 0.f, py = 0.f;
    int cur_g = __shfl(bv, 0, 64);
    int rs = base;
    for (int i = i0; i < i1; i++) {
        int k = i - i0;
        int re = __shfl(rsv, k + 1, 64);
        float di = __shfl(dv, k, 64);
        int g = __shfl(bv, k, 64);
        unsigned u0 = v2u[(size_t)i * 64 + lane];  // self term
        float ax = __uint_as_float(u0 << 16);
        float ay = __uint_as_float(u0 & 0xFFFF0000u);
        int e = rs;
        while (e < re) {
            int off = e - p0;
            if (off >= 64) {
                p0 += 64;
                buf0 = buf1;
                buf1 = (p0 + 64 + lane < segend) ? csr_src[p0 + 64 + lane] : 0;
                off -= 64;
            }
            int n = re - e;
            int avail = 64 - off;
            if (n > avail) n = avail;
            int j = 0;
            for (; j + 8 <= n; j += 8) {
                #pragma unroll
                for (int u = 0; u < 8; u++) {
                    int s = __shfl(buf0, off + j + u, 64);
                    unsigned uv = v2u[(size_t)s * 64 + lane];
                    ax += __uint_as_float(uv << 16);
                    ay += __uint_as_float(uv & 0xFFFF0000u);
                }
            }
            for (; j < n; j++) {
                int s = __shfl(buf0, off + j, 64);
                unsigned uv = v2u[(size_t)s * 64 + lane];
                ax += __uint_as_float(uv << 16);
                ay += __uint_as_float(uv & 0xFFFF0000u);
            }
            e += n;
        }
        rs = re;
        float a0 = di * ax + bb.x, a1 = di * ay + bb.y;
        float s = a0 + a1;
        #pragma unroll
        for (int m = 1; m < 64; m <<= 1) s += __shfl_xor(s, m, 64);
        float mu = s * (1.f / 128.f);
        float d0 = a0 - mu, d1 = a1 - mu;
        float q = d0 * d0 + d1 * d1;
        #pragma unroll
        for (int m = 1; m < 64; m <<= 1) q += __shfl_xor(q, m, 64);
        float r = rsqrtf(q * (1.f / 128.f) + LN_EPS);
        float o0 = fmaxf(d0 * r * gg.x + eb.x, 0.f);
        float o1 = fmaxf(d1 * r * gg.y + eb.y, 0.f);
        if (g != cur_g) {
            atomicAdd(&pooled[cur_g * DIM + 2 * lane], px);
            atomicAdd(&pooled[cur_g * DIM + 2 * lane + 1], py);
            px = 0.f; py = 0.f; cur_g = g;
        }
        px += o0; py += o1;
    }
    atomicAdd(&pooled[cur_g * DIM + 2 * lane], px);
    atomicAdd(&pooled[cur_g * DIM + 2 * lane + 1], py);
}

// ---------------- out[g] = pooled[g].fcW / max(cnt,1) + fcb ----------------
__global__ void k_out(const float* __restrict__ pooled, const int* __restrict__ starts,
                      const float* __restrict__ fcW, const float* __restrict__ fcb,
                      float* __restrict__ out) {
    int lane = threadIdx.x & 63;
    int g = (blockIdx.x * blockDim.x + threadIdx.x) >> 6;
    if (g >= N_GRAPHS) return;
    float2 p = ((const float2*)pooled)[g * 64 + lane];
    float2 w = ((const float2*)fcW)[lane];
    float s = p.x * w.x + p.y * w.y;
    #pragma unroll
    for (int m = 1; m < 64; m <<= 1) s += __shfl_xor(s, m, 64);
    if (lane == 0) {
        float c = (float)(starts[g + 1] - starts[g]);
        if (c < 1.f) c = 1.f;
        out[g] = s / c + fcb[0];
    }
}

extern "C" void kernel_launch(void* const* d_in, const int* in_sizes, int n_in,
                              void* d_out, int out_size, void* d_ws, size_t ws_size,
                              hipStream_t stream) {
    (void)in_sizes; (void)n_in; (void)out_size; (void)ws_size;
    const int* x    = (const int*)d_in[0];
    const int* src  = (const int*)d_in[1];
    const int* dst  = src + N_EDGES;
    const int* batch = (const int*)d_in[2];
    const float* emb = (const float*)d_in[3];
    const float* W1  = (const float*)d_in[4];
    const float* b1  = (const float*)d_in[5];
    const float* g1  = (const float*)d_in[6];
    const float* be1 = (const float*)d_in[7];
    const float* W2  = (const float*)d_in[8];
    const float* b2  = (const float*)d_in[9];
    const float* g2  = (const float*)d_in[10];
    const float* be2 = (const float*)d_in[11];
    const float* fcW = (const float*)d_in[12];
    const float* fcb = (const float*)d_in[13];
    float* out = (float*)d_out;

    char* wsp = (char*)d_ws;
    size_t off = 0;
    auto alloc = [&](size_t bytes) -> void* {
        void* p = wsp + off;
        off += (bytes + 15) & ~(size_t)15;
        return p;
    };
    // ---- zeroed region ----
    int*   deg      = (int*)alloc(N_NODES * 4);
    int*   cursor   = (int*)alloc(N_NODES * 4);
    float* pooled   = (float*)alloc(N_GRAPHS * DIM * 4);
    size_t zero_bytes = off;
    // ---- scratch ----
    int*      rowstart = (int*)alloc((N_NODES + 1) * 4);
    float*    dinv     = (float*)alloc(N_NODES * 4);
    unsigned* pw       = (unsigned*)alloc(N_NODES * 4);
    int*      csr_src  = (int*)alloc(N_EDGES * 4);
    float*    EW1      = (float*)alloc(VOCAB * DIM * 4);
    int*      starts   = (int*)alloc((N_GRAPHS + 1) * 4);
    int*      bsum     = (int*)alloc(NB * 4);
    int*      bofs     = (int*)alloc(NB * 4);
    unsigned short* h1b = (unsigned short*)alloc((size_t)N_NODES * DIM * 2);
    unsigned short* v2b = (unsigned short*)alloc((size_t)N_NODES * DIM * 2);

    hipMemsetAsync(d_ws, 0, zero_bytes, stream);

    k_deg<<<2048, 256, 0, stream>>>(dst, deg);
    k_starts<<<3, 256, 0, stream>>>(batch, starts);
    kb_sum<<<NB, 256, 0, stream>>>(deg, bsum);
    kb_scan<<<1, 256, 0, stream>>>(bsum, bofs, rowstart);
    kb_emit<<<NB, 256, 0, stream>>>(deg, bofs, x, rowstart, dinv, pw);
    k_scatter<<<2048, 256, 0, stream>>>(src, dst, rowstart, cursor, csr_src);
    k_ew1<<<(VOCAB * DIM + 255) / 256, 256, 0, stream>>>(emb, W1, EW1);
    k_agg1<<<768, 512, 0, stream>>>(EW1, pw, dinv, rowstart, csr_src, b1, g1, be1,
                                    (unsigned*)h1b);
    k_mm2<<<391, 512, 0, stream>>>(h1b, W2, dinv, v2b);
    {
        int nwaves = (N_NODES + SEG - 1) / SEG;          // 6250
        int nblocks = (nwaves + 3) / 4;                  // 4 waves/block
        k_agg2<<<nblocks, 256, 0, stream>>>((const unsigned*)v2b, dinv, rowstart, csr_src,
                                            batch, b2, g2, be2, pooled);
    }
    k_out<<<(N_GRAPHS * 64 + 255) / 256, 256, 0, stream>>>(pooled, starts, fcW, fcb, out);
}

// Round 10
// 270.722 us; speedup vs baseline: 1.9555x; 1.0062x over previous
//
#include <hip/hip_runtime.h>
#include <hip/hip_fp16.h>
#include <math.h>

#define N_NODES 50000
#define N_EDGES 800000
#define VOCAB 100
#define DIM 128
#define N_GRAPHS 512
#define LN_EPS 1e-5f
#define NB 196   // ceil(N_NODES/256)
#define SEG 4    // nodes per wave in k_agg2
#define NWIN 8                                   // dst windows (== XCDs)
#define WSZ ((N_NODES + NWIN - 1) / NWIN)        // 6250 nodes per window

using bf16x8  = __attribute__((ext_vector_type(8))) __bf16;
using floatx4 = __attribute__((ext_vector_type(4))) float;

__device__ __forceinline__ unsigned short f2bf(float f) {
    unsigned u = __float_as_uint(f);
    return (unsigned short)((u + 0x7FFF + ((u >> 16) & 1)) >> 16);  // RNE
}

// ---------------- degree (XCD-windowed: atomics stay in one XCD's L2) ----------------
__global__ __launch_bounds__(256) void k_deg(const int* __restrict__ dst,
                                             int* __restrict__ deg) {
    int w = blockIdx.x & (NWIN - 1);
    int bg = blockIdx.x >> 3;
    int lo = w * WSZ, hi = lo + WSZ; if (hi > N_NODES) hi = N_NODES;
    int stride = (gridDim.x >> 3) * 256;
    for (int e = bg * 256 + threadIdx.x; e < N_EDGES; e += stride) {
        int d = dst[e];
        if (d >= lo && d < hi) atomicAdd(&deg[d], 1);
    }
}

// ---------------- graph starts via binary search (batch is sorted) ----------------
__global__ void k_starts(const int* __restrict__ batch, int* __restrict__ starts) {
    int g = blockIdx.x * blockDim.x + threadIdx.x;
    if (g > N_GRAPHS) return;
    int lo = 0, hi = N_NODES;
    while (lo < hi) { int mid = (lo + hi) >> 1; if (batch[mid] < g) lo = mid + 1; else hi = mid; }
    starts[g] = lo;
}

// ---------------- 3-phase multi-block scan ----------------
__global__ __launch_bounds__(256) void kb_sum(const int* __restrict__ deg,
                                              int* __restrict__ bsum) {
    int i = blockIdx.x * 256 + threadIdx.x;
    int v = (i < N_NODES) ? deg[i] : 0;
    #pragma unroll
    for (int m = 1; m < 64; m <<= 1) v += __shfl_xor(v, m, 64);
    __shared__ int ws[4];
    int lane = threadIdx.x & 63, w = threadIdx.x >> 6;
    if (lane == 0) ws[w] = v;
    __syncthreads();
    if (threadIdx.x == 0) bsum[blockIdx.x] = ws[0] + ws[1] + ws[2] + ws[3];
}

__global__ __launch_bounds__(256) void kb_scan(const int* __restrict__ bsum,
                                               int* __restrict__ bofs,
                                               int* __restrict__ rowstart) {
    int t = threadIdx.x, lane = t & 63, w = t >> 6;
    int v = (t < NB) ? bsum[t] : 0;
    int incl = v;
    #pragma unroll
    for (int off = 1; off < 64; off <<= 1) {
        int u = __shfl_up(incl, off, 64);
        if (lane >= off) incl += u;
    }
    __shared__ int ws[4];
    if (lane == 63) ws[w] = incl;
    __syncthreads();
    int add = 0;
    for (int k = 0; k < w; k++) add += ws[k];
    incl += add;
    if (t < NB) bofs[t] = incl - v;
    if (t == 255) rowstart[N_NODES] = incl;
}

// emits rowstart, dinv (fp32), and pw[i] = (fp16(dinv_i)<<16) | x_i
__global__ __launch_bounds__(256) void kb_emit(const int* __restrict__ deg,
                                               const int* __restrict__ bofs,
                                               const int* __restrict__ x,
                                               int* __restrict__ rowstart,
                                               float* __restrict__ dinv,
                                               unsigned* __restrict__ pw) {
    int b = blockIdx.x, t = threadIdx.x, i = b * 256 + t;
    int lane = t & 63, w = t >> 6;
    int v = (i < N_NODES) ? deg[i] : 0;
    int incl = v;
    #pragma unroll
    for (int off = 1; off < 64; off <<= 1) {
        int u = __shfl_up(incl, off, 64);
        if (lane >= off) incl += u;
    }
    __shared__ int ws[4];
    if (lane == 63) ws[w] = incl;
    __syncthreads();
    int add = bofs[b];
    for (int k = 0; k < w; k++) add += ws[k];
    if (i < N_NODES) {
        rowstart[i] = add + incl - v;
        float dv = rsqrtf((float)v + 1.0f);
        dinv[i] = dv;
        unsigned hb = (unsigned)__half_as_ushort(__float2half_rn(dv));
        pw[i] = (hb << 16) | (unsigned)x[i];
    }
}

// ---------------- CSR scatter (XCD-windowed) ----------------
__global__ __launch_bounds__(256) void k_scatter(const int* __restrict__ src,
                                                 const int* __restrict__ dst,
                                                 const int* __restrict__ rowstart,
                                                 int* __restrict__ cursor,
                                                 int* __restrict__ csr_src) {
    int w = blockIdx.x & (NWIN - 1);
    int bg = blockIdx.x >> 3;
    int lo = w * WSZ, hi = lo + WSZ; if (hi > N_NODES) hi = N_NODES;
    int stride = (gridDim.x >> 3) * 256;
    for (int e = bg * 256 + threadIdx.x; e < N_EDGES; e += stride) {
        int d = dst[e];
        if (d >= lo && d < hi) {
            int pos = rowstart[d] + atomicAdd(&cursor[d], 1);
            csr_src[pos] = src[e];
        }
    }
}

// ---------------- EW1 = emb @ W1 (tiny: 100x128) ----------------
__global__ void k_ew1(const float* __restrict__ emb, const float* __restrict__ W1,
                      float* __restrict__ EW1) {
    int idx = blockIdx.x * blockDim.x + threadIdx.x;
    if (idx >= VOCAB * DIM) return;
    int r = idx >> 7, c = idx & 127;
    float acc = 0.f;
    for (int k = 0; k < DIM; k++) acc += emb[r * DIM + k] * W1[k * DIM + c];
    EW1[idx] = acc;
}

// ---------------- layer-1 agg + LN + ReLU (bf16 EW1 in LDS, bf16 h1 out) ----------------
// LDS 25.6 KB -> 32-wave/CU cap (4 blocks x 512); ds_read_b32 per edge.
__global__ __launch_bounds__(512) void k_agg1(
    const float* __restrict__ EW1, const unsigned* __restrict__ pw,
    const float* __restrict__ dinv,
    const int* __restrict__ rowstart, const int* __restrict__ csr_src,
    const float* __restrict__ b1, const float* __restrict__ g1,
    const float* __restrict__ be1, unsigned* __restrict__ h1b) {
    __shared__ unsigned ew[VOCAB * 64];  // bf16x2 packed, 25600 B
    for (int idx = threadIdx.x; idx < VOCAB * 64; idx += blockDim.x) {
        float2 v = ((const float2*)EW1)[idx];
        ew[idx] = (unsigned)f2bf(v.x) | ((unsigned)f2bf(v.y) << 16);
    }
    __syncthreads();
    int lane = threadIdx.x & 63;
    int wave = (blockIdx.x * blockDim.x + threadIdx.x) >> 6;
    int nw = (gridDim.x * blockDim.x) >> 6;
    float2 bb = make_float2(b1[2 * lane], b1[2 * lane + 1]);
    float2 gg = make_float2(g1[2 * lane], g1[2 * lane + 1]);
    float2 eb = make_float2(be1[2 * lane], be1[2 * lane + 1]);
    for (int i = wave; i < N_NODES; i += nw) {
        float di = dinv[i];
        int xi = (int)(pw[i] & 0xFFFFu);
        unsigned e0 = ew[xi * 64 + lane];
        float ax = di * __uint_as_float(e0 << 16);
        float ay = di * __uint_as_float(e0 & 0xFFFF0000u);  // self-loop
        int p = rowstart[i], pe = rowstart[i + 1];
        while (p < pe) {
            int n = pe - p; if (n > 64) n = 64;
            unsigned myw = 0;
            if (lane < n) myw = pw[csr_src[p + lane]];
            int j = 0;
            for (; j + 8 <= n; j += 8) {
                #pragma unroll
                for (int u = 0; u < 8; u++) {
                    unsigned w = (unsigned)__shfl((int)myw, j + u, 64);
                    int xv = (int)(w & 0xFFFFu);
                    float ds = __half2float(__ushort_as_half((unsigned short)(w >> 16)));
                    unsigned es = ew[xv * 64 + lane];
                    ax += ds * __uint_as_float(es << 16);
                    ay += ds * __uint_as_float(es & 0xFFFF0000u);
                }
            }
            for (; j < n; j++) {
                unsigned w = (unsigned)__shfl((int)myw, j, 64);
                int xv = (int)(w & 0xFFFFu);
                float ds = __half2float(__ushort_as_half((unsigned short)(w >> 16)));
                unsigned es = ew[xv * 64 + lane];
                ax += ds * __uint_as_float(es << 16);
                ay += ds * __uint_as_float(es & 0xFFFF0000u);
            }
            p += n;
        }
        float a0 = di * ax + bb.x, a1 = di * ay + bb.y;
        float s = a0 + a1;
        #pragma unroll
        for (int m = 1; m < 64; m <<= 1) s += __shfl_xor(s, m, 64);
        float mu = s * (1.f / 128.f);
        float d0 = a0 - mu, d1 = a1 - mu;
        float q = d0 * d0 + d1 * d1;
        #pragma unroll
        for (int m = 1; m < 64; m <<= 1) q += __shfl_xor(q, m, 64);
        float r = rsqrtf(q * (1.f / 128.f) + LN_EPS);
        float o0 = fmaxf(d0 * r * gg.x + eb.x, 0.f);
        float o1 = fmaxf(d1 * r * gg.y + eb.y, 0.f);
        h1b[(size_t)i * 64 + lane] = (unsigned)f2bf(o0) | ((unsigned)f2bf(o1) << 16);
    }
}

// ---------------- v2 = bf16( dinv * (h1 @ W2) ), MFMA 16x16x32 bf16 ----------------
#define W2K 144
__global__ __launch_bounds__(512) void k_mm2(
    const unsigned short* __restrict__ h1b, const float* __restrict__ W2,
    const float* __restrict__ dinv, unsigned short* __restrict__ v2b) {
    __shared__ unsigned short w2t[DIM * W2K];  // 36864 B
    int t = threadIdx.x;
    for (int idx = t * 4; idx < DIM * DIM; idx += 2048) {
        int k = idx >> 7, n = idx & 127;
        float4 v = *(const float4*)&W2[idx];
        w2t[(n + 0) * W2K + k] = f2bf(v.x);
        w2t[(n + 1) * W2K + k] = f2bf(v.y);
        w2t[(n + 2) * W2K + k] = f2bf(v.z);
        w2t[(n + 3) * W2K + k] = f2bf(v.w);
    }
    __syncthreads();
    int lane = t & 63, wv = t >> 6;
    int m = lane & 15, quad = lane >> 4;
    const int NT = N_NODES / 16;  // 3125 row-tiles (exact)
    for (int tile = blockIdx.x * 8 + wv; tile < NT; tile += gridDim.x * 8) {
        const unsigned short* arow = &h1b[(size_t)(tile * 16 + m) * DIM + quad * 8];
        bf16x8 a0 = *(const bf16x8*)(arow);
        bf16x8 a1 = *(const bf16x8*)(arow + 32);
        bf16x8 a2 = *(const bf16x8*)(arow + 64);
        bf16x8 a3 = *(const bf16x8*)(arow + 96);
        int r0 = tile * 16 + quad * 4;
        float dv0 = dinv[r0], dv1 = dinv[r0 + 1], dv2 = dinv[r0 + 2], dv3 = dinv[r0 + 3];
        #pragma unroll
        for (int nt = 0; nt < 8; nt++) {
            const unsigned short* brow = &w2t[(nt * 16 + m) * W2K + quad * 8];
            bf16x8 b0 = *(const bf16x8*)(brow);
            bf16x8 b1 = *(const bf16x8*)(brow + 32);
            bf16x8 b2 = *(const bf16x8*)(brow + 64);
            bf16x8 b3 = *(const bf16x8*)(brow + 96);
            floatx4 c = {0.f, 0.f, 0.f, 0.f};
            c = __builtin_amdgcn_mfma_f32_16x16x32_bf16(a0, b0, c, 0, 0, 0);
            c = __builtin_amdgcn_mfma_f32_16x16x32_bf16(a1, b1, c, 0, 0, 0);
            c = __builtin_amdgcn_mfma_f32_16x16x32_bf16(a2, b2, c, 0, 0, 0);
            c = __builtin_amdgcn_mfma_f32_16x16x32_bf16(a3, b3, c, 0, 0, 0);
            int col = nt * 16 + m;  // C/D: col=lane&15, row=quad*4+reg (m89/m91)
            v2b[(size_t)(r0 + 0) * DIM + col] = f2bf(dv0 * c[0]);
            v2b[(size_t)(r0 + 1) * DIM + col] = f2bf(dv1 * c[1]);
            v2b[(size_t)(r0 + 2) * DIM + col] = f2bf(dv2 * c[2]);
            v2b[(size_t)(r0 + 3) * DIM + col] = f2bf(dv3 * c[3]);
        }
    }
}

// ---------------- layer-2 agg: contiguous segments, dual-buffered csr chunks,
// register pool accumulation with boundary flush ----------------
__global__ __launch_bounds__(256) void k_agg2(
    const unsigned* __restrict__ v2u, const float* __restrict__ dinv,
    const int* __restrict__ rowstart, const int* __restrict__ csr_src,
    const int* __restrict__ batch,
    const float* __restrict__ b2, const float* __restrict__ g2,
    const float* __restrict__ be2, float* __restrict__ pooled) {
    int lane = threadIdx.x & 63;
    int wave = (blockIdx.x * blockDim.x + threadIdx.x) >> 6;
    int i0 = wave * SEG;
    if (i0 >= N_NODES) return;
    int i1 = i0 + SEG; if (i1 > N_NODES) i1 = N_NODES;
    int nseg = i1 - i0;

    float2 bb = make_float2(b2[2 * lane], b2[2 * lane + 1]);
    float2 gg = make_float2(g2[2 * lane], g2[2 * lane + 1]);
    float2 eb = make_float2(be2[2 * lane], be2[2 * lane + 1]);

    int rsv = 0;
    if (lane <= nseg) rsv = rowstart[i0 + lane];
    float dv = 0.f; int bv = 0;
    if (lane < nseg) { dv = dinv[i0 + lane]; bv = batch[i0 + lane]; }

    int base = __shfl(rsv, 0, 64);
    int segend = __shfl(rsv, nseg, 64);

    int p0 = base;
    int buf0 = (base + lane < segend) ? csr_src[base + lane] : 0;
    int buf1 = (base + 64 + lane < segend) ? csr_src[base + 64 + lane] : 0;

    float px = 0.f, py = 0.f;
    int cur_g = __shfl(bv, 0, 64);
    int rs = base;
    for (int i = i0; i < i1; i++) {
        int k = i - i0;
        int re = __shfl(rsv, k + 1, 64);
        float di = __shfl(dv, k, 64);
        int g = __shfl(bv, k, 64);
        unsigned u0 = v2u[(size_t)i * 64 + lane];  // self term
        float ax = __uint_as_float(u0 << 16);
        float ay = __uint_as_float(u0 & 0xFFFF0000u);
        int e = rs;
        while (e < re) {
            int off = e - p0;
            if (off >= 64) {
                p0 += 64;
                buf0 = buf1;
                buf1 = (p0 + 64 + lane < segend) ? csr_src[p0 + 64 + lane] : 0;
                off -= 64;
            }
            int n = re - e;
            int avail = 64 - off;
            if (n > avail) n = avail;
            int j = 0;
            for (; j + 8 <= n; j += 8) {
                #pragma unroll
                for (int u = 0; u < 8; u++) {
                    int s = __shfl(buf0, off + j + u, 64);
                    unsigned uv = v2u[(size_t)s * 64 + lane];
                    ax += __uint_as_float(uv << 16);
                    ay += __uint_as_float(uv & 0xFFFF0000u);
                }
            }
            for (; j < n; j++) {
                int s = __shfl(buf0, off + j, 64);
                unsigned uv = v2u[(size_t)s * 64 + lane];
                ax += __uint_as_float(uv << 16);
                ay += __uint_as_float(uv & 0xFFFF0000u);
            }
            e += n;
        }
        rs = re;
        float a0 = di * ax + bb.x, a1 = di * ay + bb.y;
        float s = a0 + a1;
        #pragma unroll
        for (int m = 1; m < 64; m <<= 1) s += __shfl_xor(s, m, 64);
        float mu = s * (1.f / 128.f);
        float d0 = a0 - mu, d1 = a1 - mu;
        float q = d0 * d0 + d1 * d1;
        #pragma unroll
        for (int m = 1; m < 64; m <<= 1) q += __shfl_xor(q, m, 64);
        float r = rsqrtf(q * (1.f / 128.f) + LN_EPS);
        float o0 = fmaxf(d0 * r * gg.x + eb.x, 0.f);
        float o1 = fmaxf(d1 * r * gg.y + eb.y, 0.f);
        if (g != cur_g) {
            atomicAdd(&pooled[cur_g * DIM + 2 * lane], px);
            atomicAdd(&pooled[cur_g * DIM + 2 * lane + 1], py);
            px = 0.f; py = 0.f; cur_g = g;
        }
        px += o0; py += o1;
    }
    atomicAdd(&pooled[cur_g * DIM + 2 * lane], px);
    atomicAdd(&pooled[cur_g * DIM + 2 * lane + 1], py);
}

// ---------------- out[g] = pooled[g].fcW / max(cnt,1) + fcb ----------------
__global__ void k_out(const float* __restrict__ pooled, const int* __restrict__ starts,
                      const float* __restrict__ fcW, const float* __restrict__ fcb,
                      float* __restrict__ out) {
    int lane = threadIdx.x & 63;
    int g = (blockIdx.x * blockDim.x + threadIdx.x) >> 6;
    if (g >= N_GRAPHS) return;
    float2 p = ((const float2*)pooled)[g * 64 + lane];
    float2 w = ((const float2*)fcW)[lane];
    float s = p.x * w.x + p.y * w.y;
    #pragma unroll
    for (int m = 1; m < 64; m <<= 1) s += __shfl_xor(s, m, 64);
    if (lane == 0) {
        float c = (float)(starts[g + 1] - starts[g]);
        if (c < 1.f) c = 1.f;
        out[g] = s / c + fcb[0];
    }
}

extern "C" void kernel_launch(void* const* d_in, const int* in_sizes, int n_in,
                              void* d_out, int out_size, void* d_ws, size_t ws_size,
                              hipStream_t stream) {
    (void)in_sizes; (void)n_in; (void)out_size; (void)ws_size;
    const int* x    = (const int*)d_in[0];
    const int* src  = (const int*)d_in[1];
    const int* dst  = src + N_EDGES;
    const int* batch = (const int*)d_in[2];
    const float* emb = (const float*)d_in[3];
    const float* W1  = (const float*)d_in[4];
    const float* b1  = (const float*)d_in[5];
    const float* g1  = (const float*)d_in[6];
    const float* be1 = (const float*)d_in[7];
    const float* W2  = (const float*)d_in[8];
    const float* b2  = (const float*)d_in[9];
    const float* g2  = (const float*)d_in[10];
    const float* be2 = (const float*)d_in[11];
    const float* fcW = (const float*)d_in[12];
    const float* fcb = (const float*)d_in[13];
    float* out = (float*)d_out;

    char* wsp = (char*)d_ws;
    size_t off = 0;
    auto alloc = [&](size_t bytes) -> void* {
        void* p = wsp + off;
        off += (bytes + 15) & ~(size_t)15;
        return p;
    };
    // ---- zeroed region ----
    int*   deg      = (int*)alloc(N_NODES * 4);
    int*   cursor   = (int*)alloc(N_NODES * 4);
    float* pooled   = (float*)alloc(N_GRAPHS * DIM * 4);
    size_t zero_bytes = off;
    // ---- scratch ----
    int*      rowstart = (int*)alloc((N_NODES + 1) * 4);
    float*    dinv     = (float*)alloc(N_NODES * 4);
    unsigned* pw       = (unsigned*)alloc(N_NODES * 4);
    int*      csr_src  = (int*)alloc(N_EDGES * 4);
    float*    EW1      = (float*)alloc(VOCAB * DIM * 4);
    int*      starts   = (int*)alloc((N_GRAPHS + 1) * 4);
    int*      bsum     = (int*)alloc(NB * 4);
    int*      bofs     = (int*)alloc(NB * 4);
    unsigned short* h1b = (unsigned short*)alloc((size_t)N_NODES * DIM * 2);
    unsigned short* v2b = (unsigned short*)alloc((size_t)N_NODES * DIM * 2);

    hipMemsetAsync(d_ws, 0, zero_bytes, stream);

    k_deg<<<2048, 256, 0, stream>>>(dst, deg);
    k_starts<<<3, 256, 0, stream>>>(batch, starts);
    kb_sum<<<NB, 256, 0, stream>>>(deg, bsum);
    kb_scan<<<1, 256, 0, stream>>>(bsum, bofs, rowstart);
    kb_emit<<<NB, 256, 0, stream>>>(deg, bofs, x, rowstart, dinv, pw);
    k_scatter<<<2048, 256, 0, stream>>>(src, dst, rowstart, cursor, csr_src);
    k_ew1<<<(VOCAB * DIM + 255) / 256, 256, 0, stream>>>(emb, W1, EW1);
    // 1024 blocks x 512 thr, 25.6 KB LDS -> 4 blocks/CU = 32 waves/CU (HW cap)
    k_agg1<<<1024, 512, 0, stream>>>(EW1, pw, dinv, rowstart, csr_src, b1, g1, be1,
                                     (unsigned*)h1b);
    k_mm2<<<391, 512, 0, stream>>>(h1b, W2, dinv, v2b);
    {
        int nwaves = (N_NODES + SEG - 1) / SEG;          // 12500
        int nblocks = (nwaves + 3) / 4;                  // 3125 blocks, 4 waves each
        k_agg2<<<nblocks, 256, 0, stream>>>((const unsigned*)v2b, dinv, rowstart, csr_src,
                                            batch, b2, g2, be2, pooled);
    }
    k_out<<<(N_GRAPHS * 64 + 255) / 256, 256, 0, stream>>>(pooled, starts, fcW, fcb, out);
}

// Round 11
// 224.279 us; speedup vs baseline: 2.3605x; 1.2071x over previous
//
#include <hip/hip_runtime.h>
#include <hip/hip_fp16.h>
#include <math.h>

#define N_NODES 50000
#define N_EDGES 800000
#define VOCAB 100
#define DIM 128
#define N_GRAPHS 512
#define LN_EPS 1e-5f
#define NB 196   // ceil(N_NODES/256)
#define SEG 4    // nodes per wave in k_agg2
#define CAP 64   // slot capacity per node (deg~Poisson(16); P(>=64)~e^-125)
#define NWIN 8                                   // dst windows (== XCDs)
#define WSZ ((N_NODES + NWIN - 1) / NWIN)        // 6250 nodes per window

using bf16x8  = __attribute__((ext_vector_type(8))) __bf16;
using floatx4 = __attribute__((ext_vector_type(4))) float;

__device__ __forceinline__ unsigned short f2bf(float f) {
    unsigned u = __float_as_uint(f);
    return (unsigned short)((u + 0x7FFF + ((u >> 16) & 1)) >> 16);  // RNE
}

// ---------------- one-pass slot-CSR build (XCD-windowed) ----------------
// cnt[d] serves as both cursor and final degree. Replaces deg+scan+scatter.
__global__ __launch_bounds__(256) void k_scatter(const int* __restrict__ src,
                                                 const int* __restrict__ dst,
                                                 int* __restrict__ cnt,
                                                 int* __restrict__ slots) {
    int w = blockIdx.x & (NWIN - 1);
    int bg = blockIdx.x >> 3;
    int lo = w * WSZ, hi = lo + WSZ; if (hi > N_NODES) hi = N_NODES;
    int stride = (gridDim.x >> 3) * 256;
    for (int e = bg * 256 + threadIdx.x; e < N_EDGES; e += stride) {
        int d = dst[e];
        if (d >= lo && d < hi) {
            int pos = atomicAdd(&cnt[d], 1);
            slots[d * CAP + pos] = src[e];
        }
    }
}

// ---------------- fused prep: dinv/pw | EW1 = emb@W1 | graph starts ----------------
__global__ __launch_bounds__(256) void k_prep(const int* __restrict__ cnt,
                                              const int* __restrict__ x,
                                              const float* __restrict__ emb,
                                              const float* __restrict__ W1,
                                              const int* __restrict__ batch,
                                              float* __restrict__ dinv,
                                              unsigned* __restrict__ pw,
                                              float* __restrict__ EW1,
                                              int* __restrict__ starts) {
    int b = blockIdx.x, t = threadIdx.x;
    if (b < NB) {                       // range 1: dinv + packed (fp16 dinv | x)
        int i = b * 256 + t;
        if (i < N_NODES) {
            float dv = rsqrtf((float)cnt[i] + 1.0f);
            dinv[i] = dv;
            unsigned hb = (unsigned)__half_as_ushort(__float2half_rn(dv));
            pw[i] = (hb << 16) | (unsigned)x[i];
        }
    } else if (b < NB + 50) {           // range 2: EW1 (100x128 = 50 blocks exactly)
        int idx = (b - NB) * 256 + t;
        int r = idx >> 7, c = idx & 127;
        float acc = 0.f;
        for (int k = 0; k < DIM; k++) acc += emb[r * DIM + k] * W1[k * DIM + c];
        EW1[idx] = acc;
    } else {                            // range 3: starts[g] via binary search
        int g = (b - NB - 50) * 256 + t;
        if (g > N_GRAPHS) return;
        int lo = 0, hi = N_NODES;
        while (lo < hi) { int mid = (lo + hi) >> 1; if (batch[mid] < g) lo = mid + 1; else hi = mid; }
        starts[g] = lo;
    }
}

// ---------------- layer-1 agg + LN + ReLU (bf16 EW1 in LDS, slot-CSR) ----------------
// 25.6 KB LDS, 512 thr -> 4 blocks/CU = 32 waves/CU. One 64-lane slot load/node.
__global__ __launch_bounds__(512) void k_agg1(
    const float* __restrict__ EW1, const unsigned* __restrict__ pw,
    const float* __restrict__ dinv, const int* __restrict__ cnt,
    const int* __restrict__ slots,
    const float* __restrict__ b1, const float* __restrict__ g1,
    const float* __restrict__ be1, unsigned* __restrict__ h1b) {
    __shared__ unsigned ew[VOCAB * 64];  // bf16x2 packed, 25600 B
    for (int idx = threadIdx.x; idx < VOCAB * 64; idx += blockDim.x) {
        float2 v = ((const float2*)EW1)[idx];
        ew[idx] = (unsigned)f2bf(v.x) | ((unsigned)f2bf(v.y) << 16);
    }
    __syncthreads();
    int lane = threadIdx.x & 63;
    int wave = (blockIdx.x * blockDim.x + threadIdx.x) >> 6;
    int nw = (gridDim.x * blockDim.x) >> 6;
    float2 bb = make_float2(b1[2 * lane], b1[2 * lane + 1]);
    float2 gg = make_float2(g1[2 * lane], g1[2 * lane + 1]);
    float2 eb = make_float2(be1[2 * lane], be1[2 * lane + 1]);
    for (int i = wave; i < N_NODES; i += nw) {
        float di = dinv[i];
        int xi = (int)(pw[i] & 0xFFFFu);
        unsigned e0 = ew[xi * 64 + lane];
        float ax = di * __uint_as_float(e0 << 16);
        float ay = di * __uint_as_float(e0 & 0xFFFF0000u);  // self-loop
        int cn = cnt[i];
        unsigned myw = 0;
        if (lane < cn) myw = pw[slots[i * CAP + lane]];
        int j = 0;
        for (; j + 8 <= cn; j += 8) {
            #pragma unroll
            for (int u = 0; u < 8; u++) {
                unsigned w = (unsigned)__shfl((int)myw, j + u, 64);
                int xv = (int)(w & 0xFFFFu);
                float ds = __half2float(__ushort_as_half((unsigned short)(w >> 16)));
                unsigned es = ew[xv * 64 + lane];
                ax += ds * __uint_as_float(es << 16);
                ay += ds * __uint_as_float(es & 0xFFFF0000u);
            }
        }
        for (; j < cn; j++) {
            unsigned w = (unsigned)__shfl((int)myw, j, 64);
            int xv = (int)(w & 0xFFFFu);
            float ds = __half2float(__ushort_as_half((unsigned short)(w >> 16)));
            unsigned es = ew[xv * 64 + lane];
            ax += ds * __uint_as_float(es << 16);
            ay += ds * __uint_as_float(es & 0xFFFF0000u);
        }
        float a0 = di * ax + bb.x, a1 = di * ay + bb.y;
        float s = a0 + a1;
        #pragma unroll
        for (int m = 1; m < 64; m <<= 1) s += __shfl_xor(s, m, 64);
        float mu = s * (1.f / 128.f);
        float d0 = a0 - mu, d1 = a1 - mu;
        float q = d0 * d0 + d1 * d1;
        #pragma unroll
        for (int m = 1; m < 64; m <<= 1) q += __shfl_xor(q, m, 64);
        float r = rsqrtf(q * (1.f / 128.f) + LN_EPS);
        float o0 = fmaxf(d0 * r * gg.x + eb.x, 0.f);
        float o1 = fmaxf(d1 * r * gg.y + eb.y, 0.f);
        h1b[i * 64 + lane] = (unsigned)f2bf(o0) | ((unsigned)f2bf(o1) << 16);
    }
}

// ---------------- v2 = bf16( dinv * (h1 @ W2) ), MFMA 16x16x32 bf16 ----------------
#define W2K 144
__global__ __launch_bounds__(512) void k_mm2(
    const unsigned short* __restrict__ h1b, const float* __restrict__ W2,
    const float* __restrict__ dinv, unsigned short* __restrict__ v2b) {
    __shared__ unsigned short w2t[DIM * W2K];  // 36864 B
    int t = threadIdx.x;
    for (int idx = t * 4; idx < DIM * DIM; idx += 2048) {
        int k = idx >> 7, n = idx & 127;
        float4 v = *(const float4*)&W2[idx];
        w2t[(n + 0) * W2K + k] = f2bf(v.x);
        w2t[(n + 1) * W2K + k] = f2bf(v.y);
        w2t[(n + 2) * W2K + k] = f2bf(v.z);
        w2t[(n + 3) * W2K + k] = f2bf(v.w);
    }
    __syncthreads();
    int lane = t & 63, wv = t >> 6;
    int m = lane & 15, quad = lane >> 4;
    const int NT = N_NODES / 16;  // 3125 row-tiles (exact)
    for (int tile = blockIdx.x * 8 + wv; tile < NT; tile += gridDim.x * 8) {
        const unsigned short* arow = &h1b[(size_t)(tile * 16 + m) * DIM + quad * 8];
        bf16x8 a0 = *(const bf16x8*)(arow);
        bf16x8 a1 = *(const bf16x8*)(arow + 32);
        bf16x8 a2 = *(const bf16x8*)(arow + 64);
        bf16x8 a3 = *(const bf16x8*)(arow + 96);
        int r0 = tile * 16 + quad * 4;
        float dv0 = dinv[r0], dv1 = dinv[r0 + 1], dv2 = dinv[r0 + 2], dv3 = dinv[r0 + 3];
        #pragma unroll
        for (int nt = 0; nt < 8; nt++) {
            const unsigned short* brow = &w2t[(nt * 16 + m) * W2K + quad * 8];
            bf16x8 b0 = *(const bf16x8*)(brow);
            bf16x8 b1 = *(const bf16x8*)(brow + 32);
            bf16x8 b2 = *(const bf16x8*)(brow + 64);
            bf16x8 b3 = *(const bf16x8*)(brow + 96);
            floatx4 c = {0.f, 0.f, 0.f, 0.f};
            c = __builtin_amdgcn_mfma_f32_16x16x32_bf16(a0, b0, c, 0, 0, 0);
            c = __builtin_amdgcn_mfma_f32_16x16x32_bf16(a1, b1, c, 0, 0, 0);
            c = __builtin_amdgcn_mfma_f32_16x16x32_bf16(a2, b2, c, 0, 0, 0);
            c = __builtin_amdgcn_mfma_f32_16x16x32_bf16(a3, b3, c, 0, 0, 0);
            int col = nt * 16 + m;  // C/D: col=lane&15, row=quad*4+reg (m89/m91)
            v2b[(size_t)(r0 + 0) * DIM + col] = f2bf(dv0 * c[0]);
            v2b[(size_t)(r0 + 1) * DIM + col] = f2bf(dv1 * c[1]);
            v2b[(size_t)(r0 + 2) * DIM + col] = f2bf(dv2 * c[2]);
            v2b[(size_t)(r0 + 3) * DIM + col] = f2bf(dv3 * c[3]);
        }
    }
}

// ---------------- layer-2 agg: slot-CSR, SEG contiguous nodes/wave,
// next-node slot prefetch, register pool accumulation with boundary flush ----------------
__global__ __launch_bounds__(256) void k_agg2(
    const unsigned* __restrict__ v2u, const float* __restrict__ dinv,
    const int* __restrict__ cnt, const int* __restrict__ slots,
    const int* __restrict__ batch,
    const float* __restrict__ b2, const float* __restrict__ g2,
    const float* __restrict__ be2, float* __restrict__ pooled) {
    int lane = threadIdx.x & 63;
    int wave = (blockIdx.x * blockDim.x + threadIdx.x) >> 6;
    int i0 = wave * SEG;
    if (i0 >= N_NODES) return;
    int i1 = i0 + SEG; if (i1 > N_NODES) i1 = N_NODES;
    int nseg = i1 - i0;

    float2 bb = make_float2(b2[2 * lane], b2[2 * lane + 1]);
    float2 gg = make_float2(g2[2 * lane], g2[2 * lane + 1]);
    float2 eb = make_float2(be2[2 * lane], be2[2 * lane + 1]);

    float dv = 0.f; int bv = 0, cv = 0;
    if (lane < nseg) {
        dv = dinv[i0 + lane]; bv = batch[i0 + lane]; cv = cnt[i0 + lane];
    }

    float px = 0.f, py = 0.f;
    int cur_g = __shfl(bv, 0, 64);
    int cn0 = __shfl(cv, 0, 64);
    int mys = (lane < cn0) ? slots[i0 * CAP + lane] : 0;
    for (int k = 0; k < nseg; k++) {
        int i = i0 + k;
        int cn = __shfl(cv, k, 64);
        float di = __shfl(dv, k, 64);
        int g = __shfl(bv, k, 64);
        // prefetch next node's slot row
        int mys_next = 0;
        if (k + 1 < nseg) {
            int cn1 = __shfl(cv, k + 1, 64);
            if (lane < cn1) mys_next = slots[(i + 1) * CAP + lane];
        }
        unsigned u0 = v2u[(size_t)i * 64 + lane];  // self term (dinv_i*hW_i folded)
        float ax = __uint_as_float(u0 << 16);
        float ay = __uint_as_float(u0 & 0xFFFF0000u);
        int j = 0;
        for (; j + 8 <= cn; j += 8) {
            #pragma unroll
            for (int u = 0; u < 8; u++) {
                int s = __shfl(mys, j + u, 64);
                unsigned uv = v2u[(size_t)s * 64 + lane];
                ax += __uint_as_float(uv << 16);
                ay += __uint_as_float(uv & 0xFFFF0000u);
            }
        }
        for (; j < cn; j++) {
            int s = __shfl(mys, j, 64);
            unsigned uv = v2u[(size_t)s * 64 + lane];
            ax += __uint_as_float(uv << 16);
            ay += __uint_as_float(uv & 0xFFFF0000u);
        }
        mys = mys_next;
        float a0 = di * ax + bb.x, a1 = di * ay + bb.y;
        float s = a0 + a1;
        #pragma unroll
        for (int m = 1; m < 64; m <<= 1) s += __shfl_xor(s, m, 64);
        float mu = s * (1.f / 128.f);
        float d0 = a0 - mu, d1 = a1 - mu;
        float q = d0 * d0 + d1 * d1;
        #pragma unroll
        for (int m = 1; m < 64; m <<= 1) q += __shfl_xor(q, m, 64);
        float r = rsqrtf(q * (1.f / 128.f) + LN_EPS);
        float o0 = fmaxf(d0 * r * gg.x + eb.x, 0.f);
        float o1 = fmaxf(d1 * r * gg.y + eb.y, 0.f);
        if (g != cur_g) {
            atomicAdd(&pooled[cur_g * DIM + 2 * lane], px);
            atomicAdd(&pooled[cur_g * DIM + 2 * lane + 1], py);
            px = 0.f; py = 0.f; cur_g = g;
        }
        px += o0; py += o1;
    }
    atomicAdd(&pooled[cur_g * DIM + 2 * lane], px);
    atomicAdd(&pooled[cur_g * DIM + 2 * lane + 1], py);
}

// ---------------- out[g] = pooled[g].fcW / max(cnt,1) + fcb ----------------
__global__ void k_out(const float* __restrict__ pooled, const int* __restrict__ starts,
                      const float* __restrict__ fcW, const float* __restrict__ fcb,
                      float* __restrict__ out) {
    int lane = threadIdx.x & 63;
    int g = (blockIdx.x * blockDim.x + threadIdx.x) >> 6;
    if (g >= N_GRAPHS) return;
    float2 p = ((const float2*)pooled)[g * 64 + lane];
    float2 w = ((const float2*)fcW)[lane];
    float s = p.x * w.x + p.y * w.y;
    #pragma unroll
    for (int m = 1; m < 64; m <<= 1) s += __shfl_xor(s, m, 64);
    if (lane == 0) {
        float c = (float)(starts[g + 1] - starts[g]);
        if (c < 1.f) c = 1.f;
        out[g] = s / c + fcb[0];
    }
}

extern "C" void kernel_launch(void* const* d_in, const int* in_sizes, int n_in,
                              void* d_out, int out_size, void* d_ws, size_t ws_size,
                              hipStream_t stream) {
    (void)in_sizes; (void)n_in; (void)out_size; (void)ws_size;
    const int* x    = (const int*)d_in[0];
    const int* src  = (const int*)d_in[1];
    const int* dst  = src + N_EDGES;
    const int* batch = (const int*)d_in[2];
    const float* emb = (const float*)d_in[3];
    const float* W1  = (const float*)d_in[4];
    const float* b1  = (const float*)d_in[5];
    const float* g1  = (const float*)d_in[6];
    const float* be1 = (const float*)d_in[7];
    const float* W2  = (const float*)d_in[8];
    const float* b2  = (const float*)d_in[9];
    const float* g2  = (const float*)d_in[10];
    const float* be2 = (const float*)d_in[11];
    const float* fcW = (const float*)d_in[12];
    const float* fcb = (const float*)d_in[13];
    float* out = (float*)d_out;

    char* wsp = (char*)d_ws;
    size_t off = 0;
    auto alloc = [&](size_t bytes) -> void* {
        void* p = wsp + off;
        off += (bytes + 15) & ~(size_t)15;
        return p;
    };
    // ---- zeroed region ----
    int*   cnt      = (int*)alloc(N_NODES * 4);
    float* pooled   = (float*)alloc(N_GRAPHS * DIM * 4);
    size_t zero_bytes = off;
    // ---- scratch ----
    float*    dinv     = (float*)alloc(N_NODES * 4);
    unsigned* pw       = (unsigned*)alloc(N_NODES * 4);
    int*      slots    = (int*)alloc((size_t)N_NODES * CAP * 4);  // 12.8 MB
    float*    EW1      = (float*)alloc(VOCAB * DIM * 4);
    int*      starts   = (int*)alloc((N_GRAPHS + 1) * 4);
    unsigned short* h1b = (unsigned short*)alloc((size_t)N_NODES * DIM * 2);
    unsigned short* v2b = (unsigned short*)alloc((size_t)N_NODES * DIM * 2);

    hipMemsetAsync(d_ws, 0, zero_bytes, stream);

    k_scatter<<<2048, 256, 0, stream>>>(src, dst, cnt, slots);
    k_prep<<<NB + 50 + 3, 256, 0, stream>>>(cnt, x, emb, W1, batch, dinv, pw, EW1, starts);
    // 1024 blocks x 512 thr, 25.6 KB LDS -> 4 blocks/CU = 32 waves/CU (HW cap)
    k_agg1<<<1024, 512, 0, stream>>>(EW1, pw, dinv, cnt, slots, b1, g1, be1,
                                     (unsigned*)h1b);
    k_mm2<<<391, 512, 0, stream>>>(h1b, W2, dinv, v2b);
    {
        int nwaves = (N_NODES + SEG - 1) / SEG;          // 12500
        int nblocks = (nwaves + 3) / 4;                  // 3125 blocks, 4 waves each
        k_agg2<<<nblocks, 256, 0, stream>>>((const unsigned*)v2b, dinv, cnt, slots,
                                            batch, b2, g2, be2, pooled);
    }
    k_out<<<(N_GRAPHS * 64 + 255) / 256, 256, 0, stream>>>(pooled, starts, fcW, fcb, out);
}